// Round 16
// baseline (207.776 us; speedup 1.0000x reference)
//
#include <hip/hip_runtime.h>
#include <cfloat>

#define M_UP   32768
#define N_DOWN 8192
#define UPC    128
#define DOWNC  256
#define OUTC   128
#define NCHUNK 8
#define CHUNK  (N_DOWN / NCHUNK)   // 1024
#define G      8                   // selection group size
#define PG     12                  // padded group stride in floats (48B)

__device__ __forceinline__ void fma4(float4& acc, float s, const float4 w) {
    acc.x = fmaf(s, w.x, acc.x);
    acc.y = fmaf(s, w.y, acc.y);
    acc.z = fmaf(s, w.z, acc.z);
    acc.w = fmaf(s, w.w, acc.w);
}

// Branchless stable top-3 insert with index tracking.
// Strict < everywhere => earlier-inserted wins ties (stable in scan order),
// matching jax.lax.top_k's lower-index-first tie-break.
__device__ __forceinline__ void top3_bl(float s, int idx,
                                        float& d0, float& d1, float& d2,
                                        int& i0, int& i1, int& i2) {
    bool c0 = s < d0, c1 = s < d1, c2 = s < d2;
    float n0 = fminf(d0, s);
    float n1 = __builtin_amdgcn_fmed3f(d0, d1, s);
    float n2 = __builtin_amdgcn_fmed3f(d1, d2, s);
    int m0 = c0 ? idx : i0;
    int m1 = c0 ? i0 : (c1 ? idx : i1);
    int m2 = c1 ? i1 : (c2 ? idx : i2);
    d0 = n0; d1 = n1; d2 = n2;
    i0 = m0; i1 = m1; i2 = m2;
}

// ---------------------------------------------------------------------------
// K0: transpose weights for coalesced float4 GEMM reads.
// ---------------------------------------------------------------------------
__global__ __launch_bounds__(256) void transpose_w(
        const float* __restrict__ W_up, const float* __restrict__ W_down,
        float* __restrict__ wt_up, float* __restrict__ wt_down) {
    int e = blockIdx.x * 256 + threadIdx.x;
    if (e < DOWNC * OUTC) {
        int k = e >> 7, c = e & 127;
        wt_down[e] = W_down[c * DOWNC + k];
    } else {
        int e2 = e - DOWNC * OUTC;
        int k = e2 >> 7, c = e2 & 127;
        wt_up[e2] = W_up[c * UPC + k];
    }
}

// ---------------------------------------------------------------------------
// R9 register-blocked GEMM tile (down-role; proven).
// ---------------------------------------------------------------------------
template <int K>
__device__ __forceinline__ void gemm_tile32(
        const float* __restrict__ A, const float* __restrict__ WT,
        float* sA /*[32*36]*/, float* sW /*[32*128]*/,
        int rbase, int tid, float4 acc[2][2]) {
    const int rl = tid & 15;
    const int c0 = (tid >> 4) * 8;
    #pragma unroll 1
    for (int ph = 0; ph < K / 32; ++ph) {
        if (ph) __syncthreads();
        {
            int r = tid >> 3, k4 = tid & 7;
            float4 v = *(const float4*)(A + (size_t)(rbase + r) * K + ph * 32 + k4 * 4);
            *(float4*)&sA[r * 36 + k4 * 4] = v;
        }
        #pragma unroll
        for (int i = 0; i < 4; ++i) {
            int idx = tid + i * 256;
            int kk = idx >> 5, cc = idx & 31;
            float4 v = *(const float4*)(WT + (size_t)(ph * 32 + kk) * OUTC + cc * 4);
            *(float4*)&sW[kk * OUTC + cc * 4] = v;
        }
        __syncthreads();
        #pragma unroll 4
        for (int kk = 0; kk < 32; ++kk) {
            float a0 = sA[rl * 36 + kk];
            float a1 = sA[(rl + 16) * 36 + kk];
            float4 w0 = *(const float4*)&sW[kk * OUTC + c0];
            float4 w1 = *(const float4*)&sW[kk * OUTC + c0 + 4];
            fma4(acc[0][0], a0, w0); fma4(acc[0][1], a0, w1);
            fma4(acc[1][0], a1, w0); fma4(acc[1][1], a1, w1);
        }
    }
}

// ---------------------------------------------------------------------------
// down_proj body (verbatim — proven inside fused_dp_knn).
// ---------------------------------------------------------------------------
__device__ __forceinline__ void down_body(
        const float* __restrict__ A, const float* __restrict__ WT,
        const float* __restrict__ bias, float* __restrict__ down_f,
        int rb, int tid, float* smem) {
    float* sA = smem;            // 1152 floats
    float* sW = smem + 1152;     // 4096 floats
    float4 acc[2][2] = {};
    gemm_tile32<DOWNC>(A, WT, sA, sW, rb * 32, tid, acc);
    const int rl = tid & 15;
    const int cg = (tid >> 4) * 2;
    const float4 b0 = ((const float4*)bias)[cg];
    const float4 b1 = ((const float4*)bias)[cg + 1];
    #pragma unroll
    for (int i = 0; i < 2; ++i) {
        const int row = rb * 32 + rl + 16 * i;
        float4 v0 = acc[i][0], v1 = acc[i][1];
        v0.x += b0.x; v0.y += b0.y; v0.z += b0.z; v0.w += b0.w;
        v1.x += b1.x; v1.y += b1.y; v1.z += b1.z; v1.w += b1.w;
        ((float4*)down_f)[row * 32 + cg] = v0;
        ((float4*)down_f)[row * 32 + cg + 1] = v1;
    }
}

// ---------------------------------------------------------------------------
// knn body, Q=4 queries/thread. R15 showed the scan's broadcast LDS reads
// still dominate the fused kernel (~46us of per-CU LDS-pipe work at Q=2).
// Q=4 halves reads/query again: same 6 b128 per 8-point group, 4 queries
// consume them. Running per-query group-min (no s[8] arrays -> no spill);
// all loops fully unrolled -> static indexing only. Group-min value and
// insert order identical to the tree form -> same selection & tie-break.
// ---------------------------------------------------------------------------
__device__ __forceinline__ void knn_body4(
        const float* __restrict__ up_points,
        const float* __restrict__ down_points,
        float2* __restrict__ part,
        int bx, int by, int tid, float* smem) {
    float* sx = smem;            // 1536
    float* sy = smem + 1536;
    float* sz = smem + 3072;
    const int base = by * CHUNK;
    for (int t = tid; t < CHUNK; t += 256) {
        int g = base + t;
        int gi = t >> 3, j = t & 7;
        sx[PG * gi + j] = down_points[3 * g];
        sy[PG * gi + j] = down_points[3 * g + 1];
        sz[PG * gi + j] = down_points[3 * g + 2];
    }
    __syncthreads();

    const int m0 = bx * 1024 + tid;              // queries m0 + 256*q
    float qx[4], qy[4], qz[4];
    #pragma unroll
    for (int q = 0; q < 4; ++q) {
        const int m = m0 + 256 * q;
        qx[q] = up_points[3 * m];
        qy[q] = up_points[3 * m + 1];
        qz[q] = up_points[3 * m + 2];
    }
    float gd0[4], gd1[4], gd2[4];
    int   gi0[4], gi1[4], gi2[4];
    #pragma unroll
    for (int q = 0; q < 4; ++q) {
        gd0[q] = FLT_MAX; gd1[q] = FLT_MAX; gd2[q] = FLT_MAX;
        gi0[q] = 0; gi1[q] = 0; gi2[q] = 0;
    }

    for (int g = 0; g < CHUNK / G; ++g) {
        float4 x0 = *(const float4*)&sx[PG * g], x1 = *(const float4*)&sx[PG * g + 4];
        float4 y0 = *(const float4*)&sy[PG * g], y1 = *(const float4*)&sy[PG * g + 4];
        float4 z0 = *(const float4*)&sz[PG * g], z1 = *(const float4*)&sz[PG * g + 4];
        float px[G] = {x0.x, x0.y, x0.z, x0.w, x1.x, x1.y, x1.z, x1.w};
        float py[G] = {y0.x, y0.y, y0.z, y0.w, y1.x, y1.y, y1.z, y1.w};
        float pz[G] = {z0.x, z0.y, z0.z, z0.w, z1.x, z1.y, z1.z, z1.w};
        float gm[4] = {FLT_MAX, FLT_MAX, FLT_MAX, FLT_MAX};
        #pragma unroll
        for (int j = 0; j < G; ++j) {
            #pragma unroll
            for (int q = 0; q < 4; ++q) {
                float dx = qx[q] - px[j], dy = qy[q] - py[j], dz = qz[q] - pz[j];
                float s = fmaf(dz, dz, fmaf(dy, dy, dx * dx));
                gm[q] = fminf(gm[q], s);
            }
        }
        #pragma unroll
        for (int q = 0; q < 4; ++q)
            top3_bl(gm[q], g, gd0[q], gd1[q], gd2[q], gi0[q], gi1[q], gi2[q]);
    }

    // exact refine over the 3 winning groups (24 points per query)
    #pragma unroll
    for (int q = 0; q < 4; ++q) {
        int bases[3] = {gi0[q], gi1[q], gi2[q]};
        float D0 = FLT_MAX, D1 = FLT_MAX, D2 = FLT_MAX;
        int I0 = 0, I1 = 0, I2 = 0;
        #pragma unroll
        for (int t3 = 0; t3 < 3; ++t3) {
            const int gb = bases[t3];
            float4 x0 = *(const float4*)&sx[PG * gb], x1 = *(const float4*)&sx[PG * gb + 4];
            float4 y0 = *(const float4*)&sy[PG * gb], y1 = *(const float4*)&sy[PG * gb + 4];
            float4 z0 = *(const float4*)&sz[PG * gb], z1 = *(const float4*)&sz[PG * gb + 4];
            float px[G] = {x0.x, x0.y, x0.z, x0.w, x1.x, x1.y, x1.z, x1.w};
            float py[G] = {y0.x, y0.y, y0.z, y0.w, y1.x, y1.y, y1.z, y1.w};
            float pz[G] = {z0.x, z0.y, z0.z, z0.w, z1.x, z1.y, z1.z, z1.w};
            #pragma unroll
            for (int j = 0; j < G; ++j) {
                float dx = qx[q] - px[j], dy = qy[q] - py[j], dz = qz[q] - pz[j];
                float s = fmaf(dz, dz, fmaf(dy, dy, dx * dx));
                top3_bl(s, base + gb * G + j, D0, D1, D2, I0, I1, I2);
            }
        }
        const int m = m0 + 256 * q;
        const int o = (by * M_UP + m) * 3;
        part[o]     = make_float2(D0, __int_as_float(I0));
        part[o + 1] = make_float2(D1, __int_as_float(I1));
        part[o + 2] = make_float2(D2, __int_as_float(I2));
    }
}

// ---------------------------------------------------------------------------
// K1+K2 fused: 256 knn (Q=4) + 256 down = 512 blocks, parity-interleaved so
// each CU hosts one of each role (down GEMM waves fill the issue slots the
// latency-bound knn scan leaves idle — R11-proven mechanism).
// ---------------------------------------------------------------------------
__global__ __launch_bounds__(256) void fused_dp_knn(
        const float* __restrict__ down_features, const float* __restrict__ wt_down,
        const float* __restrict__ b_down, float* __restrict__ down_f,
        const float* __restrict__ up_points, const float* __restrict__ down_points,
        float2* __restrict__ part) {
    __shared__ __align__(16) float smem[5248];   // max(knn 4608, down 5248) floats
    const int bid = blockIdx.x;
    const int idx = bid >> 1;
    if (bid & 1) {
        knn_body4(up_points, down_points, part, idx & 31, idx >> 5,
                  threadIdx.x, smem);
    } else {
        down_body(down_features, wt_down, b_down, down_f, idx,
                  threadIdx.x, smem);
    }
}

// ---------------------------------------------------------------------------
// K3: fused up-projection + top-3 merge + interpolation + bias + add.
// Verbatim R15 (proven best): R12 GEMM (64x128 tile, 4 rows x 8 cols) +
// LDS-staged part merge in the dead sW buffer.
// ---------------------------------------------------------------------------
__global__ __launch_bounds__(256) void up_fused(
        const float* __restrict__ A, const float* __restrict__ WT,
        const float* __restrict__ bias, const float* __restrict__ down_f,
        const float2* __restrict__ part,
        float* __restrict__ out) {
    __shared__ __align__(16) float sAT[32][72];     // [k][row], 64 rows + pad
    __shared__ __align__(16) float sW[32][128];     // [k][col]; reused for part
    const int tid = threadIdx.x;
    const int rt4 = (tid >> 4) * 4;                 // first of this thread's 4 rows
    const int ct  = tid & 15;                       // col float4 index (lo half)
    const int rbase = blockIdx.x * 64;

    float4 acc[4][2] = {};
    #pragma unroll 1
    for (int ph = 0; ph < UPC / 32; ++ph) {
        if (ph) __syncthreads();
        {   // stage A transposed: thread (r = tid&63, kq = tid>>6) loads 8 k's
            const int r = tid & 63, kq = tid >> 6;
            const float* Ar = A + (size_t)(rbase + r) * UPC + ph * 32 + kq * 8;
            float4 v0 = *(const float4*)Ar;
            float4 v1 = *(const float4*)(Ar + 4);
            const int k0 = kq * 8;
            sAT[k0 + 0][r] = v0.x; sAT[k0 + 1][r] = v0.y;
            sAT[k0 + 2][r] = v0.z; sAT[k0 + 3][r] = v0.w;
            sAT[k0 + 4][r] = v1.x; sAT[k0 + 5][r] = v1.y;
            sAT[k0 + 6][r] = v1.z; sAT[k0 + 7][r] = v1.w;
        }
        {   // stage W: contiguous float4 copies
            const float4* Wp = (const float4*)(WT + (size_t)ph * 32 * OUTC);
            float4* sW4 = (float4*)&sW[0][0];
            #pragma unroll
            for (int i = 0; i < 4; ++i)
                sW4[tid + i * 256] = Wp[tid + i * 256];
        }
        __syncthreads();
        #pragma unroll 4
        for (int kk = 0; kk < 32; ++kk) {
            float4 a  = *(const float4*)&sAT[kk][rt4];
            float4 w0 = *(const float4*)&sW[kk][ct * 4];
            float4 w1 = *(const float4*)&sW[kk][64 + ct * 4];
            fma4(acc[0][0], a.x, w0); fma4(acc[0][1], a.x, w1);
            fma4(acc[1][0], a.y, w0); fma4(acc[1][1], a.y, w1);
            fma4(acc[2][0], a.z, w0); fma4(acc[2][1], a.z, w1);
            fma4(acc[3][0], a.w, w0); fma4(acc[3][1], a.w, w1);
        }
    }

    // --- stage this block's part slice into the (now dead) sW buffer ---
    __syncthreads();                                // all k-loop sW readers done
    float2* sP = (float2*)&sW[0][0];                // 1536 float2 = 12KB <= 16KB
    #pragma unroll
    for (int i = 0; i < 6; ++i) {                   // 1536 / 256 = 6 per thread
        int t = tid + i * 256;
        int s = t / 192;                            // chunk
        int o = t - s * 192;                        // offset within 64x3 slice
        sP[t] = part[((size_t)s * M_UP + rbase) * 3 + o];
    }
    __syncthreads();

    const float4 b0 = ((const float4*)bias)[ct];
    const float4 b1 = ((const float4*)bias)[ct + 16];
    const float4* df4 = (const float4*)down_f;
    float4* out4 = (float4*)out;
    #pragma unroll
    for (int i = 0; i < 4; ++i) {                   // full unroll: static acc idx
        const int lr = rt4 + i;                     // local row 0..63
        const int m = rbase + lr;
        float D0 = FLT_MAX, D1 = FLT_MAX, D2 = FLT_MAX;
        int I0 = 0, I1 = 0, I2 = 0;
        #pragma unroll
        for (int s = 0; s < NCHUNK; ++s) {
            float2 v0 = sP[s * 192 + lr * 3];
            float2 v1 = sP[s * 192 + lr * 3 + 1];
            float2 v2 = sP[s * 192 + lr * 3 + 2];
            top3_bl(v0.x, __float_as_int(v0.y), D0, D1, D2, I0, I1, I2);
            top3_bl(v1.x, __float_as_int(v1.y), D0, D1, D2, I0, I1, I2);
            top3_bl(v2.x, __float_as_int(v2.y), D0, D1, D2, I0, I1, I2);
        }
        float r0 = 1.f / (D0 + 1e-8f);
        float r1 = 1.f / (D1 + 1e-8f);
        float r2 = 1.f / (D2 + 1e-8f);
        float rs = (r0 + r1) + r2;
        float w0 = r0 / rs, w1 = r1 / rs, w2 = r2 / rs;
        float4 f00 = df4[I0 * 32 + ct], f01 = df4[I0 * 32 + ct + 16];
        float4 f10 = df4[I1 * 32 + ct], f11 = df4[I1 * 32 + ct + 16];
        float4 f20 = df4[I2 * 32 + ct], f21 = df4[I2 * 32 + ct + 16];
        float4 res0, res1;
        res0.x = acc[i][0].x + b0.x + fmaf(w0, f00.x, fmaf(w1, f10.x, w2 * f20.x));
        res0.y = acc[i][0].y + b0.y + fmaf(w0, f00.y, fmaf(w1, f10.y, w2 * f20.y));
        res0.z = acc[i][0].z + b0.z + fmaf(w0, f00.z, fmaf(w1, f10.z, w2 * f20.z));
        res0.w = acc[i][0].w + b0.w + fmaf(w0, f00.w, fmaf(w1, f10.w, w2 * f20.w));
        res1.x = acc[i][1].x + b1.x + fmaf(w0, f01.x, fmaf(w1, f11.x, w2 * f21.x));
        res1.y = acc[i][1].y + b1.y + fmaf(w0, f01.y, fmaf(w1, f11.y, w2 * f21.y));
        res1.z = acc[i][1].z + b1.z + fmaf(w0, f01.z, fmaf(w1, f11.z, w2 * f21.z));
        res1.w = acc[i][1].w + b1.w + fmaf(w0, f01.w, fmaf(w1, f11.w, w2 * f21.w));
        out4[m * 32 + ct] = res0;
        out4[m * 32 + ct + 16] = res1;
    }
}

extern "C" void kernel_launch(void* const* d_in, const int* in_sizes, int n_in,
                              void* d_out, int out_size, void* d_ws, size_t ws_size,
                              hipStream_t stream) {
    const float* up_points     = (const float*)d_in[0];
    const float* up_features   = (const float*)d_in[1];
    const float* down_points   = (const float*)d_in[2];
    const float* down_features = (const float*)d_in[3];
    const float* W_up          = (const float*)d_in[4];
    const float* b_up          = (const float*)d_in[5];
    const float* W_down        = (const float*)d_in[6];
    const float* b_down        = (const float*)d_in[7];
    float* out = (float*)d_out;

    float* wt_down = (float*)d_ws;                         // 256*128
    float* wt_up   = wt_down + DOWNC * OUTC;               // 128*128
    float* down_f  = wt_up + UPC * OUTC;                   // 8192*128
    float2* part   = (float2*)(down_f + N_DOWN * OUTC);    // NCHUNK*32768*3 float2
    // total ~10.7 MB (proven footprint)

    transpose_w<<<(DOWNC * OUTC + UPC * OUTC) / 256, 256, 0, stream>>>(
        W_up, W_down, wt_up, wt_down);
    fused_dp_knn<<<512, 256, 0, stream>>>(
        down_features, wt_down, b_down, down_f, up_points, down_points, part);
    up_fused<<<M_UP / 64, 256, 0, stream>>>(
        up_features, wt_up, b_up, down_f, part, out);
}

// Round 17
// 173.598 us; speedup vs baseline: 1.1969x; 1.1969x over previous
//
#include <hip/hip_runtime.h>
#include <cfloat>

#define M_UP   32768
#define N_DOWN 8192
#define UPC    128
#define DOWNC  256
#define OUTC   128
#define G      8                   // selection group size
#define Q      2                   // queries per thread (amortizes LDS reads)
#define PG     12                  // padded group stride in floats (48B)

__device__ __forceinline__ void fma4(float4& acc, float s, const float4 w) {
    acc.x = fmaf(s, w.x, acc.x);
    acc.y = fmaf(s, w.y, acc.y);
    acc.z = fmaf(s, w.z, acc.z);
    acc.w = fmaf(s, w.w, acc.w);
}

// Branchless stable top-3 insert with index tracking.
// Strict < everywhere => earlier-inserted wins ties (stable in scan order),
// matching jax.lax.top_k's lower-index-first tie-break.
__device__ __forceinline__ void top3_bl(float s, int idx,
                                        float& d0, float& d1, float& d2,
                                        int& i0, int& i1, int& i2) {
    bool c0 = s < d0, c1 = s < d1, c2 = s < d2;
    float n0 = fminf(d0, s);
    float n1 = __builtin_amdgcn_fmed3f(d0, d1, s);
    float n2 = __builtin_amdgcn_fmed3f(d1, d2, s);
    int m0 = c0 ? idx : i0;
    int m1 = c0 ? i0 : (c1 ? idx : i1);
    int m2 = c1 ? i1 : (c2 ? idx : i2);
    d0 = n0; d1 = n1; d2 = n2;
    i0 = m0; i1 = m1; i2 = m2;
}

// ---------------------------------------------------------------------------
// K0: transpose weights for coalesced float4 GEMM reads.
// ---------------------------------------------------------------------------
__global__ __launch_bounds__(256) void transpose_w(
        const float* __restrict__ W_up, const float* __restrict__ W_down,
        float* __restrict__ wt_up, float* __restrict__ wt_down) {
    int e = blockIdx.x * 256 + threadIdx.x;
    if (e < DOWNC * OUTC) {
        int k = e >> 7, c = e & 127;
        wt_down[e] = W_down[c * DOWNC + k];
    } else {
        int e2 = e - DOWNC * OUTC;
        int k = e2 >> 7, c = e2 & 127;
        wt_up[e2] = W_up[c * UPC + k];
    }
}

// ---------------------------------------------------------------------------
// R9 register-blocked GEMM tile (down-role; proven).
// ---------------------------------------------------------------------------
template <int K>
__device__ __forceinline__ void gemm_tile32(
        const float* __restrict__ A, const float* __restrict__ WT,
        float* sA /*[32*36]*/, float* sW /*[32*128]*/,
        int rbase, int tid, float4 acc[2][2]) {
    const int rl = tid & 15;
    const int c0 = (tid >> 4) * 8;
    #pragma unroll 1
    for (int ph = 0; ph < K / 32; ++ph) {
        if (ph) __syncthreads();
        {
            int r = tid >> 3, k4 = tid & 7;
            float4 v = *(const float4*)(A + (size_t)(rbase + r) * K + ph * 32 + k4 * 4);
            *(float4*)&sA[r * 36 + k4 * 4] = v;
        }
        #pragma unroll
        for (int i = 0; i < 4; ++i) {
            int idx = tid + i * 256;
            int kk = idx >> 5, cc = idx & 31;
            float4 v = *(const float4*)(WT + (size_t)(ph * 32 + kk) * OUTC + cc * 4);
            *(float4*)&sW[kk * OUTC + cc * 4] = v;
        }
        __syncthreads();
        #pragma unroll 4
        for (int kk = 0; kk < 32; ++kk) {
            float a0 = sA[rl * 36 + kk];
            float a1 = sA[(rl + 16) * 36 + kk];
            float4 w0 = *(const float4*)&sW[kk * OUTC + c0];
            float4 w1 = *(const float4*)&sW[kk * OUTC + c0 + 4];
            fma4(acc[0][0], a0, w0); fma4(acc[0][1], a0, w1);
            fma4(acc[1][0], a1, w0); fma4(acc[1][1], a1, w1);
        }
    }
}

// ---------------------------------------------------------------------------
// down_proj body (verbatim — proven inside fused_dp_knn).
// ---------------------------------------------------------------------------
__device__ __forceinline__ void down_body(
        const float* __restrict__ A, const float* __restrict__ WT,
        const float* __restrict__ bias, float* __restrict__ down_f,
        int rb, int tid, float* smem) {
    float* sA = smem;            // 1152 floats
    float* sW = smem + 1152;     // 4096 floats
    float4 acc[2][2] = {};
    gemm_tile32<DOWNC>(A, WT, sA, sW, rb * 32, tid, acc);
    const int rl = tid & 15;
    const int cg = (tid >> 4) * 2;
    const float4 b0 = ((const float4*)bias)[cg];
    const float4 b1 = ((const float4*)bias)[cg + 1];
    #pragma unroll
    for (int i = 0; i < 2; ++i) {
        const int row = rb * 32 + rl + 16 * i;
        float4 v0 = acc[i][0], v1 = acc[i][1];
        v0.x += b0.x; v0.y += b0.y; v0.z += b0.z; v0.w += b0.w;
        v1.x += b1.x; v1.y += b1.y; v1.z += b1.z; v1.w += b1.w;
        ((float4*)down_f)[row * 32 + cg] = v0;
        ((float4*)down_f)[row * 32 + cg + 1] = v1;
    }
}

// ---------------------------------------------------------------------------
// knn body, Q=2 (R15-proven structure), templated on chunk count NC.
// R16 lesson: Q=4 starved occupancy (1 knn block/CU tail -> 12%). Total
// scan reads are NC-invariant; NC=16 doubles knn blocks (1024) at Q=2 so
// the mixed grid reaches 5 blocks/CU and the scan can approach its ~46us
// per-CU LDS-pipe floor.
// ---------------------------------------------------------------------------
template <int NC>
__device__ __forceinline__ void knn_bodyT(
        const float* __restrict__ up_points,
        const float* __restrict__ down_points,
        float2* __restrict__ part,
        int bx, int by, int tid, float* smem) {
    constexpr int CH = N_DOWN / NC;
    constexpr int NG = CH / G;
    float* sx = smem;
    float* sy = smem + PG * NG;
    float* sz = smem + 2 * PG * NG;
    const int base = by * CH;
    for (int t = tid; t < CH; t += 256) {
        int g = base + t;
        int gi = t >> 3, j = t & 7;
        sx[PG * gi + j] = down_points[3 * g];
        sy[PG * gi + j] = down_points[3 * g + 1];
        sz[PG * gi + j] = down_points[3 * g + 2];
    }
    __syncthreads();

    const int m0 = bx * (256 * Q) + tid;
    const int m1 = m0 + 256;
    const float q0x = up_points[3 * m0];
    const float q0y = up_points[3 * m0 + 1];
    const float q0z = up_points[3 * m0 + 2];
    const float q1x = up_points[3 * m1];
    const float q1y = up_points[3 * m1 + 1];
    const float q1z = up_points[3 * m1 + 2];

    float a_gd0 = FLT_MAX, a_gd1 = FLT_MAX, a_gd2 = FLT_MAX;
    int   a_gi0 = 0, a_gi1 = 0, a_gi2 = 0;
    float b_gd0 = FLT_MAX, b_gd1 = FLT_MAX, b_gd2 = FLT_MAX;
    int   b_gi0 = 0, b_gi1 = 0, b_gi2 = 0;

    for (int gi = 0; gi < NG; ++gi) {
        float4 x0 = *(const float4*)&sx[PG * gi], x1 = *(const float4*)&sx[PG * gi + 4];
        float4 y0 = *(const float4*)&sy[PG * gi], y1 = *(const float4*)&sy[PG * gi + 4];
        float4 z0 = *(const float4*)&sz[PG * gi], z1 = *(const float4*)&sz[PG * gi + 4];
        float px[G] = {x0.x, x0.y, x0.z, x0.w, x1.x, x1.y, x1.z, x1.w};
        float py[G] = {y0.x, y0.y, y0.z, y0.w, y1.x, y1.y, y1.z, y1.w};
        float pz[G] = {z0.x, z0.y, z0.z, z0.w, z1.x, z1.y, z1.z, z1.w};
        float s0[G], s1[G];
        #pragma unroll
        for (int j = 0; j < G; ++j) {
            float dx0 = q0x - px[j], dy0 = q0y - py[j], dz0 = q0z - pz[j];
            s0[j] = fmaf(dz0, dz0, fmaf(dy0, dy0, dx0 * dx0));
            float dx1 = q1x - px[j], dy1 = q1y - py[j], dz1 = q1z - pz[j];
            s1[j] = fmaf(dz1, dz1, fmaf(dy1, dy1, dx1 * dx1));
        }
        float gm0 = fminf(fminf(fminf(s0[0], s0[1]), fminf(s0[2], s0[3])),
                          fminf(fminf(s0[4], s0[5]), fminf(s0[6], s0[7])));
        float gm1 = fminf(fminf(fminf(s1[0], s1[1]), fminf(s1[2], s1[3])),
                          fminf(fminf(s1[4], s1[5]), fminf(s1[6], s1[7])));
        top3_bl(gm0, gi, a_gd0, a_gd1, a_gd2, a_gi0, a_gi1, a_gi2);
        top3_bl(gm1, gi, b_gd0, b_gd1, b_gd2, b_gi0, b_gi1, b_gi2);
    }

    // exact refine over the 3 winning groups (24 points per query)
    #pragma unroll
    for (int qq = 0; qq < Q; ++qq) {
        const float qx = qq ? q1x : q0x;
        const float qy = qq ? q1y : q0y;
        const float qz = qq ? q1z : q0z;
        int bases[3];
        if (qq == 0) { bases[0] = a_gi0; bases[1] = a_gi1; bases[2] = a_gi2; }
        else         { bases[0] = b_gi0; bases[1] = b_gi1; bases[2] = b_gi2; }
        float D0 = FLT_MAX, D1 = FLT_MAX, D2 = FLT_MAX;
        int I0 = 0, I1 = 0, I2 = 0;
        #pragma unroll
        for (int t3 = 0; t3 < 3; ++t3) {
            const int gb = bases[t3];
            float4 x0 = *(const float4*)&sx[PG * gb], x1 = *(const float4*)&sx[PG * gb + 4];
            float4 y0 = *(const float4*)&sy[PG * gb], y1 = *(const float4*)&sy[PG * gb + 4];
            float4 z0 = *(const float4*)&sz[PG * gb], z1 = *(const float4*)&sz[PG * gb + 4];
            float px[G] = {x0.x, x0.y, x0.z, x0.w, x1.x, x1.y, x1.z, x1.w};
            float py[G] = {y0.x, y0.y, y0.z, y0.w, y1.x, y1.y, y1.z, y1.w};
            float pz[G] = {z0.x, z0.y, z0.z, z0.w, z1.x, z1.y, z1.z, z1.w};
            #pragma unroll
            for (int j = 0; j < G; ++j) {
                float dx = qx - px[j], dy = qy - py[j], dz = qz - pz[j];
                float s = fmaf(dz, dz, fmaf(dy, dy, dx * dx));
                top3_bl(s, base + gb * G + j, D0, D1, D2, I0, I1, I2);
            }
        }
        const int m = qq ? m1 : m0;
        const int o = (by * M_UP + m) * 3;
        part[o]     = make_float2(D0, __int_as_float(I0));
        part[o + 1] = make_float2(D1, __int_as_float(I1));
        part[o + 2] = make_float2(D2, __int_as_float(I2));
    }
}

// ---------------------------------------------------------------------------
// K1+K2 fused, templated on NC.
// NC=16: 1024 knn + 256 down = 1280 blocks (5/CU), 4:1 interleave.
// NC=8 (fallback, R15-proven): 512 knn + 256 down = 768 blocks.
// ---------------------------------------------------------------------------
template <int NC>
__global__ __launch_bounds__(256) void fused_dp_knn(
        const float* __restrict__ down_features, const float* __restrict__ wt_down,
        const float* __restrict__ b_down, float* __restrict__ down_f,
        const float* __restrict__ up_points, const float* __restrict__ down_points,
        float2* __restrict__ part) {
    __shared__ __align__(16) float smem[5248];
    const int bid = blockIdx.x;
    if constexpr (NC == 8) {
        if (bid < 512) {
            knn_bodyT<8>(up_points, down_points, part, bid & 63, bid >> 6,
                         threadIdx.x, smem);
        } else {
            down_body(down_features, wt_down, b_down, down_f, bid - 512,
                      threadIdx.x, smem);
        }
    } else {
        const int grp = bid / 5, rid = bid % 5;
        if (rid < 4) {
            const int k = grp * 4 + rid;         // 0..1023
            knn_bodyT<16>(up_points, down_points, part, k & 63, k >> 6,
                          threadIdx.x, smem);
        } else {
            down_body(down_features, wt_down, b_down, down_f, grp,  // 0..255
                      threadIdx.x, smem);
        }
    }
}

// ---------------------------------------------------------------------------
// K3: fused up-projection + top-3 merge + interpolation + bias + add.
// R15 structure (proven), templated on NC. sAT/sW live in one union buffer;
// after the k-loop both are dead and the part slice (NC*64*3 float2; 12KB
// at NC=8, 24.6KB at NC=16) is staged there with coalesced loads. Merge
// order (s,j ascending) preserved -> same tie-break.
// ---------------------------------------------------------------------------
template <int NC>
__global__ __launch_bounds__(256) void up_fused(
        const float* __restrict__ A, const float* __restrict__ WT,
        const float* __restrict__ bias, const float* __restrict__ down_f,
        const float2* __restrict__ part,
        float* __restrict__ out) {
    __shared__ __align__(16) float usmem[6400];     // sAT[32*72] + sW[32*128]
    float* sAT = usmem;                             // [k][row] stride 72
    float* sW  = usmem + 2304;                      // [k][col] stride 128
    const int tid = threadIdx.x;
    const int rt4 = (tid >> 4) * 4;                 // first of this thread's 4 rows
    const int ct  = tid & 15;                       // col float4 index (lo half)
    const int rbase = blockIdx.x * 64;

    float4 acc[4][2] = {};
    #pragma unroll 1
    for (int ph = 0; ph < UPC / 32; ++ph) {
        if (ph) __syncthreads();
        {   // stage A transposed: thread (r = tid&63, kq = tid>>6) loads 8 k's
            const int r = tid & 63, kq = tid >> 6;
            const float* Ar = A + (size_t)(rbase + r) * UPC + ph * 32 + kq * 8;
            float4 v0 = *(const float4*)Ar;
            float4 v1 = *(const float4*)(Ar + 4);
            const int k0 = kq * 8;
            sAT[(k0 + 0) * 72 + r] = v0.x; sAT[(k0 + 1) * 72 + r] = v0.y;
            sAT[(k0 + 2) * 72 + r] = v0.z; sAT[(k0 + 3) * 72 + r] = v0.w;
            sAT[(k0 + 4) * 72 + r] = v1.x; sAT[(k0 + 5) * 72 + r] = v1.y;
            sAT[(k0 + 6) * 72 + r] = v1.z; sAT[(k0 + 7) * 72 + r] = v1.w;
        }
        {   // stage W: contiguous float4 copies
            const float4* Wp = (const float4*)(WT + (size_t)ph * 32 * OUTC);
            float4* sW4 = (float4*)sW;
            #pragma unroll
            for (int i = 0; i < 4; ++i)
                sW4[tid + i * 256] = Wp[tid + i * 256];
        }
        __syncthreads();
        #pragma unroll 4
        for (int kk = 0; kk < 32; ++kk) {
            float4 a  = *(const float4*)&sAT[kk * 72 + rt4];
            float4 w0 = *(const float4*)&sW[kk * 128 + ct * 4];
            float4 w1 = *(const float4*)&sW[kk * 128 + 64 + ct * 4];
            fma4(acc[0][0], a.x, w0); fma4(acc[0][1], a.x, w1);
            fma4(acc[1][0], a.y, w0); fma4(acc[1][1], a.y, w1);
            fma4(acc[2][0], a.z, w0); fma4(acc[2][1], a.z, w1);
            fma4(acc[3][0], a.w, w0); fma4(acc[3][1], a.w, w1);
        }
    }

    // --- stage this block's part slice into the (now dead) union buffer ---
    __syncthreads();                                // all k-loop smem readers done
    float2* sP = (float2*)usmem;                    // NC*192 float2 <= 3200
    #pragma unroll
    for (int i = 0; i < NC * 192 / 256; ++i) {      // 6 (NC=8) / 12 (NC=16)
        int t = tid + i * 256;
        int s = t / 192;                            // chunk
        int o = t - s * 192;                        // offset within 64x3 slice
        sP[t] = part[((size_t)s * M_UP + rbase) * 3 + o];
    }
    __syncthreads();

    const float4 b0 = ((const float4*)bias)[ct];
    const float4 b1 = ((const float4*)bias)[ct + 16];
    const float4* df4 = (const float4*)down_f;
    float4* out4 = (float4*)out;
    #pragma unroll
    for (int i = 0; i < 4; ++i) {                   // full unroll: static acc idx
        const int lr = rt4 + i;                     // local row 0..63
        const int m = rbase + lr;
        float D0 = FLT_MAX, D1 = FLT_MAX, D2 = FLT_MAX;
        int I0 = 0, I1 = 0, I2 = 0;
        #pragma unroll
        for (int s = 0; s < NC; ++s) {
            float2 v0 = sP[s * 192 + lr * 3];
            float2 v1 = sP[s * 192 + lr * 3 + 1];
            float2 v2 = sP[s * 192 + lr * 3 + 2];
            top3_bl(v0.x, __float_as_int(v0.y), D0, D1, D2, I0, I1, I2);
            top3_bl(v1.x, __float_as_int(v1.y), D0, D1, D2, I0, I1, I2);
            top3_bl(v2.x, __float_as_int(v2.y), D0, D1, D2, I0, I1, I2);
        }
        float r0 = 1.f / (D0 + 1e-8f);
        float r1 = 1.f / (D1 + 1e-8f);
        float r2 = 1.f / (D2 + 1e-8f);
        float rs = (r0 + r1) + r2;
        float w0 = r0 / rs, w1 = r1 / rs, w2 = r2 / rs;
        float4 f00 = df4[I0 * 32 + ct], f01 = df4[I0 * 32 + ct + 16];
        float4 f10 = df4[I1 * 32 + ct], f11 = df4[I1 * 32 + ct + 16];
        float4 f20 = df4[I2 * 32 + ct], f21 = df4[I2 * 32 + ct + 16];
        float4 res0, res1;
        res0.x = acc[i][0].x + b0.x + fmaf(w0, f00.x, fmaf(w1, f10.x, w2 * f20.x));
        res0.y = acc[i][0].y + b0.y + fmaf(w0, f00.y, fmaf(w1, f10.y, w2 * f20.y));
        res0.z = acc[i][0].z + b0.z + fmaf(w0, f00.z, fmaf(w1, f10.z, w2 * f20.z));
        res0.w = acc[i][0].w + b0.w + fmaf(w0, f00.w, fmaf(w1, f10.w, w2 * f20.w));
        res1.x = acc[i][1].x + b1.x + fmaf(w0, f01.x, fmaf(w1, f11.x, w2 * f21.x));
        res1.y = acc[i][1].y + b1.y + fmaf(w0, f01.y, fmaf(w1, f11.y, w2 * f21.y));
        res1.z = acc[i][1].z + b1.z + fmaf(w0, f01.z, fmaf(w1, f11.z, w2 * f21.z));
        res1.w = acc[i][1].w + b1.w + fmaf(w0, f01.w, fmaf(w1, f11.w, w2 * f21.w));
        out4[m * 32 + ct] = res0;
        out4[m * 32 + ct + 16] = res1;
    }
}

extern "C" void kernel_launch(void* const* d_in, const int* in_sizes, int n_in,
                              void* d_out, int out_size, void* d_ws, size_t ws_size,
                              hipStream_t stream) {
    const float* up_points     = (const float*)d_in[0];
    const float* up_features   = (const float*)d_in[1];
    const float* down_points   = (const float*)d_in[2];
    const float* down_features = (const float*)d_in[3];
    const float* W_up          = (const float*)d_in[4];
    const float* b_up          = (const float*)d_in[5];
    const float* W_down        = (const float*)d_in[6];
    const float* b_down        = (const float*)d_in[7];
    float* out = (float*)d_out;

    float* wt_down = (float*)d_ws;                         // 256*128
    float* wt_up   = wt_down + DOWNC * OUTC;               // 128*128
    float* down_f  = wt_up + UPC * OUTC;                   // 8192*128
    float2* part   = (float2*)(down_f + N_DOWN * OUTC);

    const size_t base_bytes =
        (size_t)(DOWNC * OUTC + UPC * OUTC + N_DOWN * OUTC) * sizeof(float);
    const size_t need16 = base_bytes + (size_t)16 * M_UP * 3 * sizeof(float2);
    const bool big = ws_size >= need16;   // ~17.2 MB for NC=16, else ~10.7 MB

    transpose_w<<<(DOWNC * OUTC + UPC * OUTC) / 256, 256, 0, stream>>>(
        W_up, W_down, wt_up, wt_down);
    if (big) {
        fused_dp_knn<16><<<1280, 256, 0, stream>>>(
            down_features, wt_down, b_down, down_f, up_points, down_points, part);
        up_fused<16><<<M_UP / 64, 256, 0, stream>>>(
            up_features, wt_up, b_up, down_f, part, out);
    } else {
        fused_dp_knn<8><<<768, 256, 0, stream>>>(
            down_features, wt_down, b_down, down_f, up_points, down_points, part);
        up_fused<8><<<M_UP / 64, 256, 0, stream>>>(
            up_features, wt_up, b_up, down_f, part, out);
    }
}

// Round 19
// 173.292 us; speedup vs baseline: 1.1990x; 1.0018x over previous
//
#include <hip/hip_runtime.h>
#include <cfloat>

#define M_UP   32768
#define N_DOWN 8192
#define UPC    128
#define DOWNC  256
#define OUTC   128
#define NCHUNK 8
#define CHUNK  (N_DOWN / NCHUNK)   // 1024
#define G      8                   // selection group size
#define Q      2                   // queries per thread (amortizes LDS reads)
#define PG     12                  // padded group stride in floats (48B)

__device__ __forceinline__ void fma4(float4& acc, float s, const float4 w) {
    acc.x = fmaf(s, w.x, acc.x);
    acc.y = fmaf(s, w.y, acc.y);
    acc.z = fmaf(s, w.z, acc.z);
    acc.w = fmaf(s, w.w, acc.w);
}

// Branchless stable top-3 insert with index tracking.
// Strict < everywhere => earlier-inserted wins ties (stable in scan order),
// matching jax.lax.top_k's lower-index-first tie-break.
__device__ __forceinline__ void top3_bl(float s, int idx,
                                        float& d0, float& d1, float& d2,
                                        int& i0, int& i1, int& i2) {
    bool c0 = s < d0, c1 = s < d1, c2 = s < d2;
    float n0 = fminf(d0, s);
    float n1 = __builtin_amdgcn_fmed3f(d0, d1, s);
    float n2 = __builtin_amdgcn_fmed3f(d1, d2, s);
    int m0 = c0 ? idx : i0;
    int m1 = c0 ? i0 : (c1 ? idx : i1);
    int m2 = c1 ? i1 : (c2 ? idx : i2);
    d0 = n0; d1 = n1; d2 = n2;
    i0 = m0; i1 = m1; i2 = m2;
}

// ---------------------------------------------------------------------------
// K0: transpose weights for coalesced float4 GEMM reads.
// ---------------------------------------------------------------------------
__global__ __launch_bounds__(256) void transpose_w(
        const float* __restrict__ W_up, const float* __restrict__ W_down,
        float* __restrict__ wt_up, float* __restrict__ wt_down) {
    int e = blockIdx.x * 256 + threadIdx.x;
    if (e < DOWNC * OUTC) {
        int k = e >> 7, c = e & 127;
        wt_down[e] = W_down[c * DOWNC + k];
    } else {
        int e2 = e - DOWNC * OUTC;
        int k = e2 >> 7, c = e2 & 127;
        wt_up[e2] = W_up[c * UPC + k];
    }
}

// ---------------------------------------------------------------------------
// R9 register-blocked GEMM tile (down-role; proven).
// ---------------------------------------------------------------------------
template <int K>
__device__ __forceinline__ void gemm_tile32(
        const float* __restrict__ A, const float* __restrict__ WT,
        float* sA /*[32*36]*/, float* sW /*[32*128]*/,
        int rbase, int tid, float4 acc[2][2]) {
    const int rl = tid & 15;
    const int c0 = (tid >> 4) * 8;
    #pragma unroll 1
    for (int ph = 0; ph < K / 32; ++ph) {
        if (ph) __syncthreads();
        {
            int r = tid >> 3, k4 = tid & 7;
            float4 v = *(const float4*)(A + (size_t)(rbase + r) * K + ph * 32 + k4 * 4);
            *(float4*)&sA[r * 36 + k4 * 4] = v;
        }
        #pragma unroll
        for (int i = 0; i < 4; ++i) {
            int idx = tid + i * 256;
            int kk = idx >> 5, cc = idx & 31;
            float4 v = *(const float4*)(WT + (size_t)(ph * 32 + kk) * OUTC + cc * 4);
            *(float4*)&sW[kk * OUTC + cc * 4] = v;
        }
        __syncthreads();
        #pragma unroll 4
        for (int kk = 0; kk < 32; ++kk) {
            float a0 = sA[rl * 36 + kk];
            float a1 = sA[(rl + 16) * 36 + kk];
            float4 w0 = *(const float4*)&sW[kk * OUTC + c0];
            float4 w1 = *(const float4*)&sW[kk * OUTC + c0 + 4];
            fma4(acc[0][0], a0, w0); fma4(acc[0][1], a0, w1);
            fma4(acc[1][0], a1, w0); fma4(acc[1][1], a1, w1);
        }
    }
}

// ---------------------------------------------------------------------------
// down_proj body (verbatim — proven inside fused_dp_knn).
// ---------------------------------------------------------------------------
__device__ __forceinline__ void down_body(
        const float* __restrict__ A, const float* __restrict__ WT,
        const float* __restrict__ bias, float* __restrict__ down_f,
        int rb, int tid, float* smem) {
    float* sA = smem;            // 1152 floats
    float* sW = smem + 1152;     // 4096 floats
    float4 acc[2][2] = {};
    gemm_tile32<DOWNC>(A, WT, sA, sW, rb * 32, tid, acc);
    const int rl = tid & 15;
    const int cg = (tid >> 4) * 2;
    const float4 b0 = ((const float4*)bias)[cg];
    const float4 b1 = ((const float4*)bias)[cg + 1];
    #pragma unroll
    for (int i = 0; i < 2; ++i) {
        const int row = rb * 32 + rl + 16 * i;
        float4 v0 = acc[i][0], v1 = acc[i][1];
        v0.x += b0.x; v0.y += b0.y; v0.z += b0.z; v0.w += b0.w;
        v1.x += b1.x; v1.y += b1.y; v1.z += b1.z; v1.w += b1.w;
        ((float4*)down_f)[row * 32 + cg] = v0;
        ((float4*)down_f)[row * 32 + cg + 1] = v1;
    }
}

// ---------------------------------------------------------------------------
// knn body (verbatim R15 — proven inside fused_dp_knn).
// ---------------------------------------------------------------------------
__device__ __forceinline__ void knn_body(
        const float* __restrict__ up_points,
        const float* __restrict__ down_points,
        float2* __restrict__ part,
        int bx, int by, int tid, float* smem) {
    float* sx = smem;            // 1536
    float* sy = smem + 1536;
    float* sz = smem + 3072;
    const int base = by * CHUNK;
    for (int t = tid; t < CHUNK; t += 256) {
        int g = base + t;
        int gi = t >> 3, j = t & 7;
        sx[PG * gi + j] = down_points[3 * g];
        sy[PG * gi + j] = down_points[3 * g + 1];
        sz[PG * gi + j] = down_points[3 * g + 2];
    }
    __syncthreads();

    const int m0 = bx * (256 * Q) + tid;
    const int m1 = m0 + 256;
    const float q0x = up_points[3 * m0];
    const float q0y = up_points[3 * m0 + 1];
    const float q0z = up_points[3 * m0 + 2];
    const float q1x = up_points[3 * m1];
    const float q1y = up_points[3 * m1 + 1];
    const float q1z = up_points[3 * m1 + 2];

    float a_gd0 = FLT_MAX, a_gd1 = FLT_MAX, a_gd2 = FLT_MAX;
    int   a_gi0 = 0, a_gi1 = 0, a_gi2 = 0;
    float b_gd0 = FLT_MAX, b_gd1 = FLT_MAX, b_gd2 = FLT_MAX;
    int   b_gi0 = 0, b_gi1 = 0, b_gi2 = 0;

    for (int gi = 0; gi < CHUNK / G; ++gi) {
        float4 x0 = *(const float4*)&sx[PG * gi], x1 = *(const float4*)&sx[PG * gi + 4];
        float4 y0 = *(const float4*)&sy[PG * gi], y1 = *(const float4*)&sy[PG * gi + 4];
        float4 z0 = *(const float4*)&sz[PG * gi], z1 = *(const float4*)&sz[PG * gi + 4];
        float px[G] = {x0.x, x0.y, x0.z, x0.w, x1.x, x1.y, x1.z, x1.w};
        float py[G] = {y0.x, y0.y, y0.z, y0.w, y1.x, y1.y, y1.z, y1.w};
        float pz[G] = {z0.x, z0.y, z0.z, z0.w, z1.x, z1.y, z1.z, z1.w};
        float s0[G], s1[G];
        #pragma unroll
        for (int j = 0; j < G; ++j) {
            float dx0 = q0x - px[j], dy0 = q0y - py[j], dz0 = q0z - pz[j];
            s0[j] = fmaf(dz0, dz0, fmaf(dy0, dy0, dx0 * dx0));
            float dx1 = q1x - px[j], dy1 = q1y - py[j], dz1 = q1z - pz[j];
            s1[j] = fmaf(dz1, dz1, fmaf(dy1, dy1, dx1 * dx1));
        }
        float gm0 = fminf(fminf(fminf(s0[0], s0[1]), fminf(s0[2], s0[3])),
                          fminf(fminf(s0[4], s0[5]), fminf(s0[6], s0[7])));
        float gm1 = fminf(fminf(fminf(s1[0], s1[1]), fminf(s1[2], s1[3])),
                          fminf(fminf(s1[4], s1[5]), fminf(s1[6], s1[7])));
        top3_bl(gm0, gi, a_gd0, a_gd1, a_gd2, a_gi0, a_gi1, a_gi2);
        top3_bl(gm1, gi, b_gd0, b_gd1, b_gd2, b_gi0, b_gi1, b_gi2);
    }

    // exact refine over the 3 winning groups (24 points per query)
    #pragma unroll
    for (int qq = 0; qq < Q; ++qq) {
        const float qx = qq ? q1x : q0x;
        const float qy = qq ? q1y : q0y;
        const float qz = qq ? q1z : q0z;
        int bases[3];
        if (qq == 0) { bases[0] = a_gi0; bases[1] = a_gi1; bases[2] = a_gi2; }
        else         { bases[0] = b_gi0; bases[1] = b_gi1; bases[2] = b_gi2; }
        float D0 = FLT_MAX, D1 = FLT_MAX, D2 = FLT_MAX;
        int I0 = 0, I1 = 0, I2 = 0;
        #pragma unroll
        for (int t3 = 0; t3 < 3; ++t3) {
            const int gb = bases[t3];
            float4 x0 = *(const float4*)&sx[PG * gb], x1 = *(const float4*)&sx[PG * gb + 4];
            float4 y0 = *(const float4*)&sy[PG * gb], y1 = *(const float4*)&sy[PG * gb + 4];
            float4 z0 = *(const float4*)&sz[PG * gb], z1 = *(const float4*)&sz[PG * gb + 4];
            float px[G] = {x0.x, x0.y, x0.z, x0.w, x1.x, x1.y, x1.z, x1.w};
            float py[G] = {y0.x, y0.y, y0.z, y0.w, y1.x, y1.y, y1.z, y1.w};
            float pz[G] = {z0.x, z0.y, z0.z, z0.w, z1.x, z1.y, z1.z, z1.w};
            #pragma unroll
            for (int j = 0; j < G; ++j) {
                float dx = qx - px[j], dy = qy - py[j], dz = qz - pz[j];
                float s = fmaf(dz, dz, fmaf(dy, dy, dx * dx));
                top3_bl(s, base + gb * G + j, D0, D1, D2, I0, I1, I2);
            }
        }
        const int m = qq ? m1 : m0;
        const int o = (by * M_UP + m) * 3;
        part[o]     = make_float2(D0, __int_as_float(I0));
        part[o + 1] = make_float2(D1, __int_as_float(I1));
        part[o + 2] = make_float2(D2, __int_as_float(I2));
    }
}

// ---------------------------------------------------------------------------
// up-GEMM body (R12 64x128 tile, 4 rows x 8 cols/thread; proven in R13 as a
// correct body): writes A@W_up + b_up directly to out. Independent of all
// other work (inputs ready at kernel start).
// ---------------------------------------------------------------------------
__device__ __forceinline__ void upg_body(
        const float* __restrict__ A, const float* __restrict__ WT,
        const float* __restrict__ bias, float* __restrict__ out,
        int rb, int tid, float* smem) {
    float* sAT = smem;              // [32][72] = 2304 floats
    float* sW  = smem + 2304;       // [32][128] = 4096 floats
    const int rt4 = (tid >> 4) * 4;
    const int ct  = tid & 15;
    const int rbase = rb * 64;

    float4 acc[4][2] = {};
    #pragma unroll 1
    for (int ph = 0; ph < UPC / 32; ++ph) {
        if (ph) __syncthreads();
        {   // stage A transposed: lane r = tid&63, kq = tid>>6 loads 8 k's
            const int r = tid & 63, kq = tid >> 6;
            const float* Ar = A + (size_t)(rbase + r) * UPC + ph * 32 + kq * 8;
            float4 v0 = *(const float4*)Ar;
            float4 v1 = *(const float4*)(Ar + 4);
            const int k0 = kq * 8;
            sAT[(k0 + 0) * 72 + r] = v0.x; sAT[(k0 + 1) * 72 + r] = v0.y;
            sAT[(k0 + 2) * 72 + r] = v0.z; sAT[(k0 + 3) * 72 + r] = v0.w;
            sAT[(k0 + 4) * 72 + r] = v1.x; sAT[(k0 + 5) * 72 + r] = v1.y;
            sAT[(k0 + 6) * 72 + r] = v1.z; sAT[(k0 + 7) * 72 + r] = v1.w;
        }
        {   // stage W
            const float4* Wp = (const float4*)(WT + (size_t)ph * 32 * OUTC);
            float4* sW4 = (float4*)sW;
            #pragma unroll
            for (int i = 0; i < 4; ++i)
                sW4[tid + i * 256] = Wp[tid + i * 256];
        }
        __syncthreads();
        #pragma unroll 4
        for (int kk = 0; kk < 32; ++kk) {
            float4 a  = *(const float4*)&sAT[kk * 72 + rt4];
            float4 w0 = *(const float4*)&sW[kk * 128 + ct * 4];
            float4 w1 = *(const float4*)&sW[kk * 128 + 64 + ct * 4];
            fma4(acc[0][0], a.x, w0); fma4(acc[0][1], a.x, w1);
            fma4(acc[1][0], a.y, w0); fma4(acc[1][1], a.y, w1);
            fma4(acc[2][0], a.z, w0); fma4(acc[2][1], a.z, w1);
            fma4(acc[3][0], a.w, w0); fma4(acc[3][1], a.w, w1);
        }
    }
    const float4 b0 = ((const float4*)bias)[ct];
    const float4 b1 = ((const float4*)bias)[ct + 16];
    float4* out4 = (float4*)out;
    #pragma unroll
    for (int i = 0; i < 4; ++i) {
        const int m = rbase + rt4 + i;
        float4 v0 = acc[i][0], v1 = acc[i][1];
        v0.x += b0.x; v0.y += b0.y; v0.z += b0.z; v0.w += b0.w;
        v1.x += b1.x; v1.y += b1.y; v1.z += b1.z; v1.w += b1.w;
        out4[m * 32 + ct] = v0;
        out4[m * 32 + ct + 16] = v1;
    }
}

// ---------------------------------------------------------------------------
// K1+K2+K3a: 512 knn blocks + 256 down blocks (R15-proven split). NEW: each
// down block, after down_body (~25us), runs TWO 64-row up-GEMM tiles in its
// idle tail (knn runs ~70us) — R11's fill-the-idle-issue-slots mechanism
// applied temporally, with ZERO extra blocks (avoids R13's residency
// collapse). 2 tiles x 256 blocks = all 512 tiles; up-GEMM writes A@W+b
// directly to out. Barriers separate body phases (smem reuse); the bid
// branch is block-uniform so all barriers are convergent.
// ---------------------------------------------------------------------------
__global__ __launch_bounds__(256) void fused_dp_knn(
        const float* __restrict__ down_features, const float* __restrict__ wt_down,
        const float* __restrict__ b_down, float* __restrict__ down_f,
        const float* __restrict__ up_points, const float* __restrict__ down_points,
        float2* __restrict__ part,
        const float* __restrict__ up_features, const float* __restrict__ wt_up,
        const float* __restrict__ b_up, float* __restrict__ out) {
    __shared__ __align__(16) float smem[6400];   // max(knn 4608, down 5248, upg 6400)
    const int bid = blockIdx.x;
    if (bid < 512) {
        knn_body(up_points, down_points, part, bid & 63, bid >> 6,
                 threadIdx.x, smem);
    } else {
        const int db = bid - 512;                // 0..255
        down_body(down_features, wt_down, b_down, down_f, db,
                  threadIdx.x, smem);
        __syncthreads();                         // drain down_body smem readers
        upg_body(up_features, wt_up, b_up, out, 2 * db, threadIdx.x, smem);
        __syncthreads();
        upg_body(up_features, wt_up, b_up, out, 2 * db + 1, threadIdx.x, smem);
    }
}

// ---------------------------------------------------------------------------
// K3b: merge partial top-3 + interpolate + out += (in place). 64 rows/block
// (512 blocks). part slice staged to LDS with coalesced loads (R15-proven
// epilogue pattern). Merge order (s,j ascending) -> identical tie-break.
// ---------------------------------------------------------------------------
__global__ __launch_bounds__(256) void merge_out64(
        const float* __restrict__ down_f, const float2* __restrict__ part,
        float* __restrict__ out) {
    __shared__ __align__(16) float2 sP[NCHUNK * 192];   // 12 KB
    const int tid = threadIdx.x;
    const int rbase = blockIdx.x * 64;
    #pragma unroll
    for (int i = 0; i < 6; ++i) {
        int t = tid + i * 256;
        int s = t / 192;
        int o = t - s * 192;
        sP[t] = part[((size_t)s * M_UP + rbase) * 3 + o];
    }
    __syncthreads();

    const int rt4 = (tid >> 4) * 4;
    const int ct  = tid & 15;
    const float4* df4 = (const float4*)down_f;
    float4* out4 = (float4*)out;
    #pragma unroll
    for (int i = 0; i < 4; ++i) {
        const int lr = rt4 + i;                  // local row 0..63
        const int m = rbase + lr;
        float D0 = FLT_MAX, D1 = FLT_MAX, D2 = FLT_MAX;
        int I0 = 0, I1 = 0, I2 = 0;
        #pragma unroll
        for (int s = 0; s < NCHUNK; ++s) {
            float2 v0 = sP[s * 192 + lr * 3];
            float2 v1 = sP[s * 192 + lr * 3 + 1];
            float2 v2 = sP[s * 192 + lr * 3 + 2];
            top3_bl(v0.x, __float_as_int(v0.y), D0, D1, D2, I0, I1, I2);
            top3_bl(v1.x, __float_as_int(v1.y), D0, D1, D2, I0, I1, I2);
            top3_bl(v2.x, __float_as_int(v2.y), D0, D1, D2, I0, I1, I2);
        }
        float r0 = 1.f / (D0 + 1e-8f);
        float r1 = 1.f / (D1 + 1e-8f);
        float r2 = 1.f / (D2 + 1e-8f);
        float rs = (r0 + r1) + r2;
        float w0 = r0 / rs, w1 = r1 / rs, w2 = r2 / rs;
        float4 f00 = df4[I0 * 32 + ct], f01 = df4[I0 * 32 + ct + 16];
        float4 f10 = df4[I1 * 32 + ct], f11 = df4[I1 * 32 + ct + 16];
        float4 f20 = df4[I2 * 32 + ct], f21 = df4[I2 * 32 + ct + 16];
        float4 o0 = out4[m * 32 + ct];
        float4 o1 = out4[m * 32 + ct + 16];
        o0.x += fmaf(w0, f00.x, fmaf(w1, f10.x, w2 * f20.x));
        o0.y += fmaf(w0, f00.y, fmaf(w1, f10.y, w2 * f20.y));
        o0.z += fmaf(w0, f00.z, fmaf(w1, f10.z, w2 * f20.z));
        o0.w += fmaf(w0, f00.w, fmaf(w1, f10.w, w2 * f20.w));
        o1.x += fmaf(w0, f01.x, fmaf(w1, f11.x, w2 * f21.x));
        o1.y += fmaf(w0, f01.y, fmaf(w1, f11.y, w2 * f21.y));
        o1.z += fmaf(w0, f01.z, fmaf(w1, f11.z, w2 * f21.z));
        o1.w += fmaf(w0, f01.w, fmaf(w1, f11.w, w2 * f21.w));
        out4[m * 32 + ct] = o0;
        out4[m * 32 + ct + 16] = o1;
    }
}

extern "C" void kernel_launch(void* const* d_in, const int* in_sizes, int n_in,
                              void* d_out, int out_size, void* d_ws, size_t ws_size,
                              hipStream_t stream) {
    const float* up_points     = (const float*)d_in[0];
    const float* up_features   = (const float*)d_in[1];
    const float* down_points   = (const float*)d_in[2];
    const float* down_features = (const float*)d_in[3];
    const float* W_up          = (const float*)d_in[4];
    const float* b_up          = (const float*)d_in[5];
    const float* W_down        = (const float*)d_in[6];
    const float* b_down        = (const float*)d_in[7];
    float* out = (float*)d_out;

    float* wt_down = (float*)d_ws;                         // 256*128
    float* wt_up   = wt_down + DOWNC * OUTC;               // 128*128
    float* down_f  = wt_up + UPC * OUTC;                   // 8192*128
    float2* part   = (float2*)(down_f + N_DOWN * OUTC);    // NCHUNK*32768*3 float2
    // total ~10.7 MB (proven footprint)

    transpose_w<<<(DOWNC * OUTC + UPC * OUTC) / 256, 256, 0, stream>>>(
        W_up, W_down, wt_up, wt_down);
    fused_dp_knn<<<768, 256, 0, stream>>>(
        down_features, wt_down, b_down, down_f, up_points, down_points, part,
        up_features, wt_up, b_up, out);
    merge_out64<<<M_UP / 64, 256, 0, stream>>>(down_f, part, out);
}

// Round 20
// 165.127 us; speedup vs baseline: 1.2583x; 1.0494x over previous
//
#include <hip/hip_runtime.h>
#include <cfloat>

#define M_UP   32768
#define N_DOWN 8192
#define UPC    128
#define DOWNC  256
#define OUTC   128
#define NCHUNK 8
#define CHUNK  (N_DOWN / NCHUNK)   // 1024
#define G      8                   // selection group size
#define Q      2                   // queries per thread (amortizes LDS reads)
#define PG     12                  // padded group stride in floats (48B)

__device__ __forceinline__ void fma4(float4& acc, float s, const float4 w) {
    acc.x = fmaf(s, w.x, acc.x);
    acc.y = fmaf(s, w.y, acc.y);
    acc.z = fmaf(s, w.z, acc.z);
    acc.w = fmaf(s, w.w, acc.w);
}

// Branchless stable top-3 insert with index tracking.
// Strict < everywhere => earlier-inserted wins ties (stable in scan order),
// matching jax.lax.top_k's lower-index-first tie-break.
__device__ __forceinline__ void top3_bl(float s, int idx,
                                        float& d0, float& d1, float& d2,
                                        int& i0, int& i1, int& i2) {
    bool c0 = s < d0, c1 = s < d1, c2 = s < d2;
    float n0 = fminf(d0, s);
    float n1 = __builtin_amdgcn_fmed3f(d0, d1, s);
    float n2 = __builtin_amdgcn_fmed3f(d1, d2, s);
    int m0 = c0 ? idx : i0;
    int m1 = c0 ? i0 : (c1 ? idx : i1);
    int m2 = c1 ? i1 : (c2 ? idx : i2);
    d0 = n0; d1 = n1; d2 = n2;
    i0 = m0; i1 = m1; i2 = m2;
}

// ---------------------------------------------------------------------------
// K0: transpose weights for coalesced float4 GEMM reads.
// ---------------------------------------------------------------------------
__global__ __launch_bounds__(256) void transpose_w(
        const float* __restrict__ W_up, const float* __restrict__ W_down,
        float* __restrict__ wt_up, float* __restrict__ wt_down) {
    int e = blockIdx.x * 256 + threadIdx.x;
    if (e < DOWNC * OUTC) {
        int k = e >> 7, c = e & 127;
        wt_down[e] = W_down[c * DOWNC + k];
    } else {
        int e2 = e - DOWNC * OUTC;
        int k = e2 >> 7, c = e2 & 127;
        wt_up[e2] = W_up[c * UPC + k];
    }
}

// ---------------------------------------------------------------------------
// R9 register-blocked GEMM tile (down-role; proven).
// ---------------------------------------------------------------------------
template <int K>
__device__ __forceinline__ void gemm_tile32(
        const float* __restrict__ A, const float* __restrict__ WT,
        float* sA /*[32*36]*/, float* sW /*[32*128]*/,
        int rbase, int tid, float4 acc[2][2]) {
    const int rl = tid & 15;
    const int c0 = (tid >> 4) * 8;
    #pragma unroll 1
    for (int ph = 0; ph < K / 32; ++ph) {
        if (ph) __syncthreads();
        {
            int r = tid >> 3, k4 = tid & 7;
            float4 v = *(const float4*)(A + (size_t)(rbase + r) * K + ph * 32 + k4 * 4);
            *(float4*)&sA[r * 36 + k4 * 4] = v;
        }
        #pragma unroll
        for (int i = 0; i < 4; ++i) {
            int idx = tid + i * 256;
            int kk = idx >> 5, cc = idx & 31;
            float4 v = *(const float4*)(WT + (size_t)(ph * 32 + kk) * OUTC + cc * 4);
            *(float4*)&sW[kk * OUTC + cc * 4] = v;
        }
        __syncthreads();
        #pragma unroll 4
        for (int kk = 0; kk < 32; ++kk) {
            float a0 = sA[rl * 36 + kk];
            float a1 = sA[(rl + 16) * 36 + kk];
            float4 w0 = *(const float4*)&sW[kk * OUTC + c0];
            float4 w1 = *(const float4*)&sW[kk * OUTC + c0 + 4];
            fma4(acc[0][0], a0, w0); fma4(acc[0][1], a0, w1);
            fma4(acc[1][0], a1, w0); fma4(acc[1][1], a1, w1);
        }
    }
}

// ---------------------------------------------------------------------------
// down_proj body (verbatim — proven inside fused_dp_knn).
// ---------------------------------------------------------------------------
__device__ __forceinline__ void down_body(
        const float* __restrict__ A, const float* __restrict__ WT,
        const float* __restrict__ bias, float* __restrict__ down_f,
        int rb, int tid, float* smem) {
    float* sA = smem;            // 1152 floats
    float* sW = smem + 1152;     // 4096 floats
    float4 acc[2][2] = {};
    gemm_tile32<DOWNC>(A, WT, sA, sW, rb * 32, tid, acc);
    const int rl = tid & 15;
    const int cg = (tid >> 4) * 2;
    const float4 b0 = ((const float4*)bias)[cg];
    const float4 b1 = ((const float4*)bias)[cg + 1];
    #pragma unroll
    for (int i = 0; i < 2; ++i) {
        const int row = rb * 32 + rl + 16 * i;
        float4 v0 = acc[i][0], v1 = acc[i][1];
        v0.x += b0.x; v0.y += b0.y; v0.z += b0.z; v0.w += b0.w;
        v1.x += b1.x; v1.y += b1.y; v1.z += b1.z; v1.w += b1.w;
        ((float4*)down_f)[row * 32 + cg] = v0;
        ((float4*)down_f)[row * 32 + cg + 1] = v1;
    }
}

// ---------------------------------------------------------------------------
// knn body (verbatim — proven inside fused_dp_knn).
// ---------------------------------------------------------------------------
__device__ __forceinline__ void knn_body(
        const float* __restrict__ up_points,
        const float* __restrict__ down_points,
        float2* __restrict__ part,
        int bx, int by, int tid, float* smem) {
    float* sx = smem;            // 1536
    float* sy = smem + 1536;
    float* sz = smem + 3072;
    const int base = by * CHUNK;
    for (int t = tid; t < CHUNK; t += 256) {
        int g = base + t;
        int gi = t >> 3, j = t & 7;
        sx[PG * gi + j] = down_points[3 * g];
        sy[PG * gi + j] = down_points[3 * g + 1];
        sz[PG * gi + j] = down_points[3 * g + 2];
    }
    __syncthreads();

    const int m0 = bx * (256 * Q) + tid;
    const int m1 = m0 + 256;
    const float q0x = up_points[3 * m0];
    const float q0y = up_points[3 * m0 + 1];
    const float q0z = up_points[3 * m0 + 2];
    const float q1x = up_points[3 * m1];
    const float q1y = up_points[3 * m1 + 1];
    const float q1z = up_points[3 * m1 + 2];

    float a_gd0 = FLT_MAX, a_gd1 = FLT_MAX, a_gd2 = FLT_MAX;
    int   a_gi0 = 0, a_gi1 = 0, a_gi2 = 0;
    float b_gd0 = FLT_MAX, b_gd1 = FLT_MAX, b_gd2 = FLT_MAX;
    int   b_gi0 = 0, b_gi1 = 0, b_gi2 = 0;

    for (int gi = 0; gi < CHUNK / G; ++gi) {
        float4 x0 = *(const float4*)&sx[PG * gi], x1 = *(const float4*)&sx[PG * gi + 4];
        float4 y0 = *(const float4*)&sy[PG * gi], y1 = *(const float4*)&sy[PG * gi + 4];
        float4 z0 = *(const float4*)&sz[PG * gi], z1 = *(const float4*)&sz[PG * gi + 4];
        float px[G] = {x0.x, x0.y, x0.z, x0.w, x1.x, x1.y, x1.z, x1.w};
        float py[G] = {y0.x, y0.y, y0.z, y0.w, y1.x, y1.y, y1.z, y1.w};
        float pz[G] = {z0.x, z0.y, z0.z, z0.w, z1.x, z1.y, z1.z, z1.w};
        float s0[G], s1[G];
        #pragma unroll
        for (int j = 0; j < G; ++j) {
            float dx0 = q0x - px[j], dy0 = q0y - py[j], dz0 = q0z - pz[j];
            s0[j] = fmaf(dz0, dz0, fmaf(dy0, dy0, dx0 * dx0));
            float dx1 = q1x - px[j], dy1 = q1y - py[j], dz1 = q1z - pz[j];
            s1[j] = fmaf(dz1, dz1, fmaf(dy1, dy1, dx1 * dx1));
        }
        float gm0 = fminf(fminf(fminf(s0[0], s0[1]), fminf(s0[2], s0[3])),
                          fminf(fminf(s0[4], s0[5]), fminf(s0[6], s0[7])));
        float gm1 = fminf(fminf(fminf(s1[0], s1[1]), fminf(s1[2], s1[3])),
                          fminf(fminf(s1[4], s1[5]), fminf(s1[6], s1[7])));
        top3_bl(gm0, gi, a_gd0, a_gd1, a_gd2, a_gi0, a_gi1, a_gi2);
        top3_bl(gm1, gi, b_gd0, b_gd1, b_gd2, b_gi0, b_gi1, b_gi2);
    }

    // exact refine over the 3 winning groups (24 points per query)
    #pragma unroll
    for (int qq = 0; qq < Q; ++qq) {
        const float qx = qq ? q1x : q0x;
        const float qy = qq ? q1y : q0y;
        const float qz = qq ? q1z : q0z;
        int bases[3];
        if (qq == 0) { bases[0] = a_gi0; bases[1] = a_gi1; bases[2] = a_gi2; }
        else         { bases[0] = b_gi0; bases[1] = b_gi1; bases[2] = b_gi2; }
        float D0 = FLT_MAX, D1 = FLT_MAX, D2 = FLT_MAX;
        int I0 = 0, I1 = 0, I2 = 0;
        #pragma unroll
        for (int t3 = 0; t3 < 3; ++t3) {
            const int gb = bases[t3];
            float4 x0 = *(const float4*)&sx[PG * gb], x1 = *(const float4*)&sx[PG * gb + 4];
            float4 y0 = *(const float4*)&sy[PG * gb], y1 = *(const float4*)&sy[PG * gb + 4];
            float4 z0 = *(const float4*)&sz[PG * gb], z1 = *(const float4*)&sz[PG * gb + 4];
            float px[G] = {x0.x, x0.y, x0.z, x0.w, x1.x, x1.y, x1.z, x1.w};
            float py[G] = {y0.x, y0.y, y0.z, y0.w, y1.x, y1.y, y1.z, y1.w};
            float pz[G] = {z0.x, z0.y, z0.z, z0.w, z1.x, z1.y, z1.z, z1.w};
            #pragma unroll
            for (int j = 0; j < G; ++j) {
                float dx = qx - px[j], dy = qy - py[j], dz = qz - pz[j];
                float s = fmaf(dz, dz, fmaf(dy, dy, dx * dx));
                top3_bl(s, base + gb * G + j, D0, D1, D2, I0, I1, I2);
            }
        }
        const int m = qq ? m1 : m0;
        const int o = (by * M_UP + m) * 3;
        part[o]     = make_float2(D0, __int_as_float(I0));
        part[o + 1] = make_float2(D1, __int_as_float(I1));
        part[o + 2] = make_float2(D2, __int_as_float(I2));
    }
}

// ---------------------------------------------------------------------------
// K1+K2 fused (verbatim R11/R15 — measured 67.5-69.5us, down-role ~free).
// R13 (3-role), R16 (Q=4), R17 (NC=16), R19 (upg tail) all regressed vs
// this configuration: knn is at its LDS/VALU mixed floor and the per-CU LDS
// pipe is the shared resource — adding more LDS consumers to the same CUs
// lengthens the critical path instead of hiding under it.
// ---------------------------------------------------------------------------
__global__ __launch_bounds__(256) void fused_dp_knn(
        const float* __restrict__ down_features, const float* __restrict__ wt_down,
        const float* __restrict__ b_down, float* __restrict__ down_f,
        const float* __restrict__ up_points, const float* __restrict__ down_points,
        float2* __restrict__ part) {
    __shared__ __align__(16) float smem[5248];   // max(knn 4608, down 5248) floats
    const int bid = blockIdx.x;
    if (bid < 512) {
        knn_body(up_points, down_points, part, bid & 63, bid >> 6,
                 threadIdx.x, smem);
    } else {
        down_body(down_features, wt_down, b_down, down_f, bid - 512,
                  threadIdx.x, smem);
    }
}

// ---------------------------------------------------------------------------
// K3: fused up-projection + top-3 merge + interpolation + bias + add.
// Verbatim R15 (session best, 164.6us): R12 GEMM (64x128 tile, 4 rows x
// 8 cols/thread, transposed-A LDS) + LDS-staged part merge in the dead
// sW buffer. Merge order (s,j ascending) -> same tie-break as reference.
// ---------------------------------------------------------------------------
__global__ __launch_bounds__(256) void up_fused(
        const float* __restrict__ A, const float* __restrict__ WT,
        const float* __restrict__ bias, const float* __restrict__ down_f,
        const float2* __restrict__ part,
        float* __restrict__ out) {
    __shared__ __align__(16) float sAT[32][72];     // [k][row], 64 rows + pad
    __shared__ __align__(16) float sW[32][128];     // [k][col]; reused for part
    const int tid = threadIdx.x;
    const int rt4 = (tid >> 4) * 4;                 // first of this thread's 4 rows
    const int ct  = tid & 15;                       // col float4 index (lo half)
    const int rbase = blockIdx.x * 64;

    float4 acc[4][2] = {};
    #pragma unroll 1
    for (int ph = 0; ph < UPC / 32; ++ph) {
        if (ph) __syncthreads();
        {   // stage A transposed: thread (r = tid&63, kq = tid>>6) loads 8 k's
            const int r = tid & 63, kq = tid >> 6;
            const float* Ar = A + (size_t)(rbase + r) * UPC + ph * 32 + kq * 8;
            float4 v0 = *(const float4*)Ar;
            float4 v1 = *(const float4*)(Ar + 4);
            const int k0 = kq * 8;
            sAT[k0 + 0][r] = v0.x; sAT[k0 + 1][r] = v0.y;
            sAT[k0 + 2][r] = v0.z; sAT[k0 + 3][r] = v0.w;
            sAT[k0 + 4][r] = v1.x; sAT[k0 + 5][r] = v1.y;
            sAT[k0 + 6][r] = v1.z; sAT[k0 + 7][r] = v1.w;
        }
        {   // stage W: contiguous float4 copies
            const float4* Wp = (const float4*)(WT + (size_t)ph * 32 * OUTC);
            float4* sW4 = (float4*)&sW[0][0];
            #pragma unroll
            for (int i = 0; i < 4; ++i)
                sW4[tid + i * 256] = Wp[tid + i * 256];
        }
        __syncthreads();
        #pragma unroll 4
        for (int kk = 0; kk < 32; ++kk) {
            float4 a  = *(const float4*)&sAT[kk][rt4];
            float4 w0 = *(const float4*)&sW[kk][ct * 4];
            float4 w1 = *(const float4*)&sW[kk][64 + ct * 4];
            fma4(acc[0][0], a.x, w0); fma4(acc[0][1], a.x, w1);
            fma4(acc[1][0], a.y, w0); fma4(acc[1][1], a.y, w1);
            fma4(acc[2][0], a.z, w0); fma4(acc[2][1], a.z, w1);
            fma4(acc[3][0], a.w, w0); fma4(acc[3][1], a.w, w1);
        }
    }

    // --- stage this block's part slice into the (now dead) sW buffer ---
    __syncthreads();                                // all k-loop sW readers done
    float2* sP = (float2*)&sW[0][0];                // 1536 float2 = 12KB <= 16KB
    #pragma unroll
    for (int i = 0; i < 6; ++i) {                   // 1536 / 256 = 6 per thread
        int t = tid + i * 256;
        int s = t / 192;                            // chunk
        int o = t - s * 192;                        // offset within 64x3 slice
        sP[t] = part[((size_t)s * M_UP + rbase) * 3 + o];
    }
    __syncthreads();

    const float4 b0 = ((const float4*)bias)[ct];
    const float4 b1 = ((const float4*)bias)[ct + 16];
    const float4* df4 = (const float4*)down_f;
    float4* out4 = (float4*)out;
    #pragma unroll
    for (int i = 0; i < 4; ++i) {                   // full unroll: static acc idx
        const int lr = rt4 + i;                     // local row 0..63
        const int m = rbase + lr;
        float D0 = FLT_MAX, D1 = FLT_MAX, D2 = FLT_MAX;
        int I0 = 0, I1 = 0, I2 = 0;
        #pragma unroll
        for (int s = 0; s < NCHUNK; ++s) {
            float2 v0 = sP[s * 192 + lr * 3];
            float2 v1 = sP[s * 192 + lr * 3 + 1];
            float2 v2 = sP[s * 192 + lr * 3 + 2];
            top3_bl(v0.x, __float_as_int(v0.y), D0, D1, D2, I0, I1, I2);
            top3_bl(v1.x, __float_as_int(v1.y), D0, D1, D2, I0, I1, I2);
            top3_bl(v2.x, __float_as_int(v2.y), D0, D1, D2, I0, I1, I2);
        }
        float r0 = 1.f / (D0 + 1e-8f);
        float r1 = 1.f / (D1 + 1e-8f);
        float r2 = 1.f / (D2 + 1e-8f);
        float rs = (r0 + r1) + r2;
        float w0 = r0 / rs, w1 = r1 / rs, w2 = r2 / rs;
        float4 f00 = df4[I0 * 32 + ct], f01 = df4[I0 * 32 + ct + 16];
        float4 f10 = df4[I1 * 32 + ct], f11 = df4[I1 * 32 + ct + 16];
        float4 f20 = df4[I2 * 32 + ct], f21 = df4[I2 * 32 + ct + 16];
        float4 res0, res1;
        res0.x = acc[i][0].x + b0.x + fmaf(w0, f00.x, fmaf(w1, f10.x, w2 * f20.x));
        res0.y = acc[i][0].y + b0.y + fmaf(w0, f00.y, fmaf(w1, f10.y, w2 * f20.y));
        res0.z = acc[i][0].z + b0.z + fmaf(w0, f00.z, fmaf(w1, f10.z, w2 * f20.z));
        res0.w = acc[i][0].w + b0.w + fmaf(w0, f00.w, fmaf(w1, f10.w, w2 * f20.w));
        res1.x = acc[i][1].x + b1.x + fmaf(w0, f01.x, fmaf(w1, f11.x, w2 * f21.x));
        res1.y = acc[i][1].y + b1.y + fmaf(w0, f01.y, fmaf(w1, f11.y, w2 * f21.y));
        res1.z = acc[i][1].z + b1.z + fmaf(w0, f01.z, fmaf(w1, f11.z, w2 * f21.z));
        res1.w = acc[i][1].w + b1.w + fmaf(w0, f01.w, fmaf(w1, f11.w, w2 * f21.w));
        out4[m * 32 + ct] = res0;
        out4[m * 32 + ct + 16] = res1;
    }
}

extern "C" void kernel_launch(void* const* d_in, const int* in_sizes, int n_in,
                              void* d_out, int out_size, void* d_ws, size_t ws_size,
                              hipStream_t stream) {
    const float* up_points     = (const float*)d_in[0];
    const float* up_features   = (const float*)d_in[1];
    const float* down_points   = (const float*)d_in[2];
    const float* down_features = (const float*)d_in[3];
    const float* W_up          = (const float*)d_in[4];
    const float* b_up          = (const float*)d_in[5];
    const float* W_down        = (const float*)d_in[6];
    const float* b_down        = (const float*)d_in[7];
    float* out = (float*)d_out;

    float* wt_down = (float*)d_ws;                         // 256*128
    float* wt_up   = wt_down + DOWNC * OUTC;               // 128*128
    float* down_f  = wt_up + UPC * OUTC;                   // 8192*128
    float2* part   = (float2*)(down_f + N_DOWN * OUTC);    // NCHUNK*32768*3 float2
    // total ~10.7 MB (proven footprint)

    transpose_w<<<(DOWNC * OUTC + UPC * OUTC) / 256, 256, 0, stream>>>(
        W_up, W_down, wt_up, wt_down);
    fused_dp_knn<<<768, 256, 0, stream>>>(
        down_features, wt_down, b_down, down_f, up_points, down_points, part);
    up_fused<<<M_UP / 64, 256, 0, stream>>>(
        up_features, wt_up, b_up, down_f, part, out);
}

// Round 21
// 163.394 us; speedup vs baseline: 1.2716x; 1.0106x over previous
//
#include <hip/hip_runtime.h>
#include <cfloat>

#define M_UP   32768
#define N_DOWN 8192
#define UPC    128
#define DOWNC  256
#define OUTC   128
#define NCHUNK 8
#define CHUNK  (N_DOWN / NCHUNK)   // 1024
#define G      8                   // selection group size
#define Q      2                   // queries per thread (amortizes LDS reads)
#define PG     12                  // padded group stride in floats (48B)

__device__ __forceinline__ void fma4(float4& acc, float s, const float4 w) {
    acc.x = fmaf(s, w.x, acc.x);
    acc.y = fmaf(s, w.y, acc.y);
    acc.z = fmaf(s, w.z, acc.z);
    acc.w = fmaf(s, w.w, acc.w);
}

// Branchless stable top-3 insert with index tracking.
// Strict < everywhere => earlier-inserted wins ties (stable in scan order),
// matching jax.lax.top_k's lower-index-first tie-break.
__device__ __forceinline__ void top3_bl(float s, int idx,
                                        float& d0, float& d1, float& d2,
                                        int& i0, int& i1, int& i2) {
    bool c0 = s < d0, c1 = s < d1, c2 = s < d2;
    float n0 = fminf(d0, s);
    float n1 = __builtin_amdgcn_fmed3f(d0, d1, s);
    float n2 = __builtin_amdgcn_fmed3f(d1, d2, s);
    int m0 = c0 ? idx : i0;
    int m1 = c0 ? i0 : (c1 ? idx : i1);
    int m2 = c1 ? i1 : (c2 ? idx : i2);
    d0 = n0; d1 = n1; d2 = n2;
    i0 = m0; i1 = m1; i2 = m2;
}

// ---------------------------------------------------------------------------
// Register-blocked GEMM tile with INLINE W-transpose staging (R21):
// 32 rows x 128 cols, per-thread 2x8. W is the untransposed torch layout
// [OUTC][K]; each thread reads 16 k's of one output-channel row (coalesced
// 4x float4) and writes them transposed into sW[k][c] as 16 ds_write_b32
// (lanes hit 32 consecutive c -> conflict-free; the two k-halves alias
// 2-way = free, m136). Replaces the standalone transpose_w kernel:
// +45cy/thread/phase (~0.6us/CU) in exchange for one fewer dispatch.
// ---------------------------------------------------------------------------
template <int K>
__device__ __forceinline__ void gemm_tile32_wt(
        const float* __restrict__ A, const float* __restrict__ W,
        float* sA /*[32*36]*/, float* sW /*[32*128]*/,
        int rbase, int tid, float4 acc[2][2]) {
    const int rl = tid & 15;
    const int c0 = (tid >> 4) * 8;
    const int wc = tid >> 1;                 // output channel 0..127
    const int wh = (tid & 1) * 16;           // k-half within the 32-k phase
    #pragma unroll 1
    for (int ph = 0; ph < K / 32; ++ph) {
        if (ph) __syncthreads();
        {   // stage A: 32 rows x 32 k (1 float4/thread, 128B segments)
            int r = tid >> 3, k4 = tid & 7;
            float4 v = *(const float4*)(A + (size_t)(rbase + r) * K + ph * 32 + k4 * 4);
            *(float4*)&sA[r * 36 + k4 * 4] = v;
        }
        {   // stage W transposed: sW[k][c] from W[c][k]
            const float* Wr = W + (size_t)wc * K + ph * 32 + wh;
            float4 v0 = *(const float4*)(Wr);
            float4 v1 = *(const float4*)(Wr + 4);
            float4 v2 = *(const float4*)(Wr + 8);
            float4 v3 = *(const float4*)(Wr + 12);
            sW[(wh + 0) * OUTC + wc] = v0.x;  sW[(wh + 1) * OUTC + wc] = v0.y;
            sW[(wh + 2) * OUTC + wc] = v0.z;  sW[(wh + 3) * OUTC + wc] = v0.w;
            sW[(wh + 4) * OUTC + wc] = v1.x;  sW[(wh + 5) * OUTC + wc] = v1.y;
            sW[(wh + 6) * OUTC + wc] = v1.z;  sW[(wh + 7) * OUTC + wc] = v1.w;
            sW[(wh + 8) * OUTC + wc] = v2.x;  sW[(wh + 9) * OUTC + wc] = v2.y;
            sW[(wh + 10) * OUTC + wc] = v2.z; sW[(wh + 11) * OUTC + wc] = v2.w;
            sW[(wh + 12) * OUTC + wc] = v3.x; sW[(wh + 13) * OUTC + wc] = v3.y;
            sW[(wh + 14) * OUTC + wc] = v3.z; sW[(wh + 15) * OUTC + wc] = v3.w;
        }
        __syncthreads();
        #pragma unroll 4
        for (int kk = 0; kk < 32; ++kk) {
            float a0 = sA[rl * 36 + kk];
            float a1 = sA[(rl + 16) * 36 + kk];
            float4 w0 = *(const float4*)&sW[kk * OUTC + c0];
            float4 w1 = *(const float4*)&sW[kk * OUTC + c0 + 4];
            fma4(acc[0][0], a0, w0); fma4(acc[0][1], a0, w1);
            fma4(acc[1][0], a1, w0); fma4(acc[1][1], a1, w1);
        }
    }
}

// ---------------------------------------------------------------------------
// down_proj body (R9 structure + inline W-transpose staging).
// ---------------------------------------------------------------------------
__device__ __forceinline__ void down_body(
        const float* __restrict__ A, const float* __restrict__ W,
        const float* __restrict__ bias, float* __restrict__ down_f,
        int rb, int tid, float* smem) {
    float* sA = smem;            // 1152 floats
    float* sW = smem + 1152;     // 4096 floats
    float4 acc[2][2] = {};
    gemm_tile32_wt<DOWNC>(A, W, sA, sW, rb * 32, tid, acc);
    const int rl = tid & 15;
    const int cg = (tid >> 4) * 2;
    const float4 b0 = ((const float4*)bias)[cg];
    const float4 b1 = ((const float4*)bias)[cg + 1];
    #pragma unroll
    for (int i = 0; i < 2; ++i) {
        const int row = rb * 32 + rl + 16 * i;
        float4 v0 = acc[i][0], v1 = acc[i][1];
        v0.x += b0.x; v0.y += b0.y; v0.z += b0.z; v0.w += b0.w;
        v1.x += b1.x; v1.y += b1.y; v1.z += b1.z; v1.w += b1.w;
        ((float4*)down_f)[row * 32 + cg] = v0;
        ((float4*)down_f)[row * 32 + cg + 1] = v1;
    }
}

// ---------------------------------------------------------------------------
// knn body (verbatim — proven inside fused_dp_knn at ~68us).
// ---------------------------------------------------------------------------
__device__ __forceinline__ void knn_body(
        const float* __restrict__ up_points,
        const float* __restrict__ down_points,
        float2* __restrict__ part,
        int bx, int by, int tid, float* smem) {
    float* sx = smem;            // 1536
    float* sy = smem + 1536;
    float* sz = smem + 3072;
    const int base = by * CHUNK;
    for (int t = tid; t < CHUNK; t += 256) {
        int g = base + t;
        int gi = t >> 3, j = t & 7;
        sx[PG * gi + j] = down_points[3 * g];
        sy[PG * gi + j] = down_points[3 * g + 1];
        sz[PG * gi + j] = down_points[3 * g + 2];
    }
    __syncthreads();

    const int m0 = bx * (256 * Q) + tid;
    const int m1 = m0 + 256;
    const float q0x = up_points[3 * m0];
    const float q0y = up_points[3 * m0 + 1];
    const float q0z = up_points[3 * m0 + 2];
    const float q1x = up_points[3 * m1];
    const float q1y = up_points[3 * m1 + 1];
    const float q1z = up_points[3 * m1 + 2];

    float a_gd0 = FLT_MAX, a_gd1 = FLT_MAX, a_gd2 = FLT_MAX;
    int   a_gi0 = 0, a_gi1 = 0, a_gi2 = 0;
    float b_gd0 = FLT_MAX, b_gd1 = FLT_MAX, b_gd2 = FLT_MAX;
    int   b_gi0 = 0, b_gi1 = 0, b_gi2 = 0;

    for (int gi = 0; gi < CHUNK / G; ++gi) {
        float4 x0 = *(const float4*)&sx[PG * gi], x1 = *(const float4*)&sx[PG * gi + 4];
        float4 y0 = *(const float4*)&sy[PG * gi], y1 = *(const float4*)&sy[PG * gi + 4];
        float4 z0 = *(const float4*)&sz[PG * gi], z1 = *(const float4*)&sz[PG * gi + 4];
        float px[G] = {x0.x, x0.y, x0.z, x0.w, x1.x, x1.y, x1.z, x1.w};
        float py[G] = {y0.x, y0.y, y0.z, y0.w, y1.x, y1.y, y1.z, y1.w};
        float pz[G] = {z0.x, z0.y, z0.z, z0.w, z1.x, z1.y, z1.z, z1.w};
        float s0[G], s1[G];
        #pragma unroll
        for (int j = 0; j < G; ++j) {
            float dx0 = q0x - px[j], dy0 = q0y - py[j], dz0 = q0z - pz[j];
            s0[j] = fmaf(dz0, dz0, fmaf(dy0, dy0, dx0 * dx0));
            float dx1 = q1x - px[j], dy1 = q1y - py[j], dz1 = q1z - pz[j];
            s1[j] = fmaf(dz1, dz1, fmaf(dy1, dy1, dx1 * dx1));
        }
        float gm0 = fminf(fminf(fminf(s0[0], s0[1]), fminf(s0[2], s0[3])),
                          fminf(fminf(s0[4], s0[5]), fminf(s0[6], s0[7])));
        float gm1 = fminf(fminf(fminf(s1[0], s1[1]), fminf(s1[2], s1[3])),
                          fminf(fminf(s1[4], s1[5]), fminf(s1[6], s1[7])));
        top3_bl(gm0, gi, a_gd0, a_gd1, a_gd2, a_gi0, a_gi1, a_gi2);
        top3_bl(gm1, gi, b_gd0, b_gd1, b_gd2, b_gi0, b_gi1, b_gi2);
    }

    // exact refine over the 3 winning groups (24 points per query)
    #pragma unroll
    for (int qq = 0; qq < Q; ++qq) {
        const float qx = qq ? q1x : q0x;
        const float qy = qq ? q1y : q0y;
        const float qz = qq ? q1z : q0z;
        int bases[3];
        if (qq == 0) { bases[0] = a_gi0; bases[1] = a_gi1; bases[2] = a_gi2; }
        else         { bases[0] = b_gi0; bases[1] = b_gi1; bases[2] = b_gi2; }
        float D0 = FLT_MAX, D1 = FLT_MAX, D2 = FLT_MAX;
        int I0 = 0, I1 = 0, I2 = 0;
        #pragma unroll
        for (int t3 = 0; t3 < 3; ++t3) {
            const int gb = bases[t3];
            float4 x0 = *(const float4*)&sx[PG * gb], x1 = *(const float4*)&sx[PG * gb + 4];
            float4 y0 = *(const float4*)&sy[PG * gb], y1 = *(const float4*)&sy[PG * gb + 4];
            float4 z0 = *(const float4*)&sz[PG * gb], z1 = *(const float4*)&sz[PG * gb + 4];
            float px[G] = {x0.x, x0.y, x0.z, x0.w, x1.x, x1.y, x1.z, x1.w};
            float py[G] = {y0.x, y0.y, y0.z, y0.w, y1.x, y1.y, y1.z, y1.w};
            float pz[G] = {z0.x, z0.y, z0.z, z0.w, z1.x, z1.y, z1.z, z1.w};
            #pragma unroll
            for (int j = 0; j < G; ++j) {
                float dx = qx - px[j], dy = qy - py[j], dz = qz - pz[j];
                float s = fmaf(dz, dz, fmaf(dy, dy, dx * dx));
                top3_bl(s, base + gb * G + j, D0, D1, D2, I0, I1, I2);
            }
        }
        const int m = qq ? m1 : m0;
        const int o = (by * M_UP + m) * 3;
        part[o]     = make_float2(D0, __int_as_float(I0));
        part[o + 1] = make_float2(D1, __int_as_float(I1));
        part[o + 2] = make_float2(D2, __int_as_float(I2));
    }
}

// ---------------------------------------------------------------------------
// K1+K2 fused (R15-proven 512 knn + 256 down split; down-role ~free).
// W_down now consumed untransposed via inline-transpose staging.
// ---------------------------------------------------------------------------
__global__ __launch_bounds__(256) void fused_dp_knn(
        const float* __restrict__ down_features, const float* __restrict__ W_down,
        const float* __restrict__ b_down, float* __restrict__ down_f,
        const float* __restrict__ up_points, const float* __restrict__ down_points,
        float2* __restrict__ part) {
    __shared__ __align__(16) float smem[5248];   // max(knn 4608, down 5248) floats
    const int bid = blockIdx.x;
    if (bid < 512) {
        knn_body(up_points, down_points, part, bid & 63, bid >> 6,
                 threadIdx.x, smem);
    } else {
        down_body(down_features, W_down, b_down, down_f, bid - 512,
                  threadIdx.x, smem);
    }
}

// ---------------------------------------------------------------------------
// K3: fused up-projection + top-3 merge + interpolation + bias + add.
// R15 structure (session best); W_up staged with the same inline transpose
// (16 b32 writes, conflict-free pattern). Merge order (s,j ascending)
// preserved -> same tie-break as reference.
// ---------------------------------------------------------------------------
__global__ __launch_bounds__(256) void up_fused(
        const float* __restrict__ A, const float* __restrict__ W,
        const float* __restrict__ bias, const float* __restrict__ down_f,
        const float2* __restrict__ part,
        float* __restrict__ out) {
    __shared__ __align__(16) float sAT[32][72];     // [k][row], 64 rows + pad
    __shared__ __align__(16) float sW[32][128];     // [k][col]; reused for part
    const int tid = threadIdx.x;
    const int rt4 = (tid >> 4) * 4;                 // first of this thread's 4 rows
    const int ct  = tid & 15;                       // col float4 index (lo half)
    const int wc  = tid >> 1;                       // staging: output channel
    const int wh  = (tid & 1) * 16;                 // staging: k-half
    const int rbase = blockIdx.x * 64;

    float4 acc[4][2] = {};
    #pragma unroll 1
    for (int ph = 0; ph < UPC / 32; ++ph) {
        if (ph) __syncthreads();
        {   // stage A transposed: thread (r = tid&63, kq = tid>>6) loads 8 k's
            const int r = tid & 63, kq = tid >> 6;
            const float* Ar = A + (size_t)(rbase + r) * UPC + ph * 32 + kq * 8;
            float4 v0 = *(const float4*)Ar;
            float4 v1 = *(const float4*)(Ar + 4);
            const int k0 = kq * 8;
            sAT[k0 + 0][r] = v0.x; sAT[k0 + 1][r] = v0.y;
            sAT[k0 + 2][r] = v0.z; sAT[k0 + 3][r] = v0.w;
            sAT[k0 + 4][r] = v1.x; sAT[k0 + 5][r] = v1.y;
            sAT[k0 + 6][r] = v1.z; sAT[k0 + 7][r] = v1.w;
        }
        {   // stage W transposed: sW[k][c] from W[c][k]
            const float* Wr = W + (size_t)wc * UPC + ph * 32 + wh;
            float4 v0 = *(const float4*)(Wr);
            float4 v1 = *(const float4*)(Wr + 4);
            float4 v2 = *(const float4*)(Wr + 8);
            float4 v3 = *(const float4*)(Wr + 12);
            sW[wh + 0][wc] = v0.x;  sW[wh + 1][wc] = v0.y;
            sW[wh + 2][wc] = v0.z;  sW[wh + 3][wc] = v0.w;
            sW[wh + 4][wc] = v1.x;  sW[wh + 5][wc] = v1.y;
            sW[wh + 6][wc] = v1.z;  sW[wh + 7][wc] = v1.w;
            sW[wh + 8][wc] = v2.x;  sW[wh + 9][wc] = v2.y;
            sW[wh + 10][wc] = v2.z; sW[wh + 11][wc] = v2.w;
            sW[wh + 12][wc] = v3.x; sW[wh + 13][wc] = v3.y;
            sW[wh + 14][wc] = v3.z; sW[wh + 15][wc] = v3.w;
        }
        __syncthreads();
        #pragma unroll 4
        for (int kk = 0; kk < 32; ++kk) {
            float4 a  = *(const float4*)&sAT[kk][rt4];
            float4 w0 = *(const float4*)&sW[kk][ct * 4];
            float4 w1 = *(const float4*)&sW[kk][64 + ct * 4];
            fma4(acc[0][0], a.x, w0); fma4(acc[0][1], a.x, w1);
            fma4(acc[1][0], a.y, w0); fma4(acc[1][1], a.y, w1);
            fma4(acc[2][0], a.z, w0); fma4(acc[2][1], a.z, w1);
            fma4(acc[3][0], a.w, w0); fma4(acc[3][1], a.w, w1);
        }
    }

    // --- stage this block's part slice into the (now dead) sW buffer ---
    __syncthreads();                                // all k-loop sW readers done
    float2* sP = (float2*)&sW[0][0];                // 1536 float2 = 12KB <= 16KB
    #pragma unroll
    for (int i = 0; i < 6; ++i) {                   // 1536 / 256 = 6 per thread
        int t = tid + i * 256;
        int s = t / 192;                            // chunk
        int o = t - s * 192;                        // offset within 64x3 slice
        sP[t] = part[((size_t)s * M_UP + rbase) * 3 + o];
    }
    __syncthreads();

    const float4 b0 = ((const float4*)bias)[ct];
    const float4 b1 = ((const float4*)bias)[ct + 16];
    const float4* df4 = (const float4*)down_f;
    float4* out4 = (float4*)out;
    #pragma unroll
    for (int i = 0; i < 4; ++i) {                   // full unroll: static acc idx
        const int lr = rt4 + i;                     // local row 0..63
        const int m = rbase + lr;
        float D0 = FLT_MAX, D1 = FLT_MAX, D2 = FLT_MAX;
        int I0 = 0, I1 = 0, I2 = 0;
        #pragma unroll
        for (int s = 0; s < NCHUNK; ++s) {
            float2 v0 = sP[s * 192 + lr * 3];
            float2 v1 = sP[s * 192 + lr * 3 + 1];
            float2 v2 = sP[s * 192 + lr * 3 + 2];
            top3_bl(v0.x, __float_as_int(v0.y), D0, D1, D2, I0, I1, I2);
            top3_bl(v1.x, __float_as_int(v1.y), D0, D1, D2, I0, I1, I2);
            top3_bl(v2.x, __float_as_int(v2.y), D0, D1, D2, I0, I1, I2);
        }
        float r0 = 1.f / (D0 + 1e-8f);
        float r1 = 1.f / (D1 + 1e-8f);
        float r2 = 1.f / (D2 + 1e-8f);
        float rs = (r0 + r1) + r2;
        float w0 = r0 / rs, w1 = r1 / rs, w2 = r2 / rs;
        float4 f00 = df4[I0 * 32 + ct], f01 = df4[I0 * 32 + ct + 16];
        float4 f10 = df4[I1 * 32 + ct], f11 = df4[I1 * 32 + ct + 16];
        float4 f20 = df4[I2 * 32 + ct], f21 = df4[I2 * 32 + ct + 16];
        float4 res0, res1;
        res0.x = acc[i][0].x + b0.x + fmaf(w0, f00.x, fmaf(w1, f10.x, w2 * f20.x));
        res0.y = acc[i][0].y + b0.y + fmaf(w0, f00.y, fmaf(w1, f10.y, w2 * f20.y));
        res0.z = acc[i][0].z + b0.z + fmaf(w0, f00.z, fmaf(w1, f10.z, w2 * f20.z));
        res0.w = acc[i][0].w + b0.w + fmaf(w0, f00.w, fmaf(w1, f10.w, w2 * f20.w));
        res1.x = acc[i][1].x + b1.x + fmaf(w0, f01.x, fmaf(w1, f11.x, w2 * f21.x));
        res1.y = acc[i][1].y + b1.y + fmaf(w0, f01.y, fmaf(w1, f11.y, w2 * f21.y));
        res1.z = acc[i][1].z + b1.z + fmaf(w0, f01.z, fmaf(w1, f11.z, w2 * f21.z));
        res1.w = acc[i][1].w + b1.w + fmaf(w0, f01.w, fmaf(w1, f11.w, w2 * f21.w));
        out4[m * 32 + ct] = res0;
        out4[m * 32 + ct + 16] = res1;
    }
}

extern "C" void kernel_launch(void* const* d_in, const int* in_sizes, int n_in,
                              void* d_out, int out_size, void* d_ws, size_t ws_size,
                              hipStream_t stream) {
    const float* up_points     = (const float*)d_in[0];
    const float* up_features   = (const float*)d_in[1];
    const float* down_points   = (const float*)d_in[2];
    const float* down_features = (const float*)d_in[3];
    const float* W_up          = (const float*)d_in[4];
    const float* b_up          = (const float*)d_in[5];
    const float* W_down        = (const float*)d_in[6];
    const float* b_down        = (const float*)d_in[7];
    float* out = (float*)d_out;

    float* down_f = (float*)d_ws;                          // 8192*128
    float2* part  = (float2*)(down_f + N_DOWN * OUTC);     // NCHUNK*32768*3 float2
    // total ~10.5 MB (wt buffers eliminated — W transposed inline in LDS)

    fused_dp_knn<<<768, 256, 0, stream>>>(
        down_features, W_down, b_down, down_f, up_points, down_points, part);
    up_fused<<<M_UP / 64, 256, 0, stream>>>(
        up_features, W_up, b_up, down_f, part, out);
}